// Round 13
// baseline (344.224 us; speedup 1.0000x reference)
//
#include <hip/hip_runtime.h>

#define NT    8192
#define NP    8200
#define NPP   8320          // 65*128 = 260*32 = 520*16
#define NB    64
#define DV    64
#define NL    4
#define TFR   520
#define KSP   65            // partial count (one per k_inv block-column)
#define KSPV  26            // k-splits for v-DFT (26*10 = 260 steps)
#define SPBV  10
#define PI2   6.28318530717958647692f

typedef _Float16 half8 __attribute__((ext_vector_type(8)));
typedef _Float16 half4 __attribute__((ext_vector_type(4)));
typedef float    f32x4 __attribute__((ext_vector_type(4)));

// ---------------- workspace layout (bytes) ----------------
// xT    : [NB][NPP][DV] f16                68,157,440
// tabF  : [260][8][64][8] f16               2,129,920
// tabI  : [4][520][64][8] f16 (alpha)       2,129,920
// Wfrag : [NL][2][2][4][64][8] f16            131,072
// zfrag : [NB][4][4][64][8] f16             1,048,576
// xpf   : [65][NB][4][2048] f16            68,157,440  (frag order)
// Vpart : [26][NB][128] f16                   425,984
// G     : [128] f32 ; A : [3][64] f32
static const size_t B_XT   = 0;
static const size_t B_TABF = 68157440ull;
static const size_t B_TABI = B_TABF + 2129920ull;
static const size_t B_WFR  = B_TABI + 2129920ull;
static const size_t B_ZFR  = B_WFR  + 131072ull;
static const size_t B_XPF  = B_ZFR  + 1048576ull;
static const size_t B_VP   = B_XPF  + 68157440ull;
static const size_t B_G    = B_VP   + 425984ull;
static const size_t B_A    = B_G    + 512ull;

// ---------------- trig tables, output-major (one coalesced half8 per thread) ----------------
__global__ void k_prep(_Float16* __restrict__ tabF, _Float16* __restrict__ tabI) {
    int idx = blockIdx.x * 256 + threadIdx.x;
    if (idx < 133120) {                       // tabF: [260 gs][8 cf][64 lane][8 j]
        int lane = idx & 63;
        int rest = idx >> 6;
        int cf = rest & 7, gs = rest >> 3;
        int ml = lane & 15, lh = lane >> 4;
        int m = cf * 16 + ml, k = m >> 1, comp = m & 1;
        half8 o;
        #pragma unroll
        for (int j = 0; j < 8; ++j) {
            int t = gs * 32 + lh * 8 + j;
            float val = 0.f;
            if (t < NP) {
                int mm = (int)(((long long)t * (long long)k) % NP);
                float th = (float)mm * (PI2 / (float)NP);
                float sn, cs; sincosf(th, &sn, &cs);
                val = comp ? sn : cs;
            }
            o[j] = (_Float16)val;
        }
        *(half8*)&tabF[(size_t)idx * 8] = o;
    } else if (idx < 266240) {                // tabI: [4 ks][520 tf][64 lane][8 j], alpha folded
        int id2 = idx - 133120;
        int lane = id2 & 63;
        int rest = id2 >> 6;
        int tf = rest % 520, ks = rest / 520;
        int lt = lane & 15, mh = lane >> 4;
        int t = tf * 16 + lt;
        half8 o;
        #pragma unroll
        for (int j = 0; j < 8; ++j) {
            int m = ks * 32 + mh * 8 + j;
            int k = m >> 1, comp = m & 1;
            float val = 0.f;
            if (t < NP) {
                int mm = (int)(((long long)t * (long long)k) % NP);
                float th = (float)mm * (PI2 / (float)NP);
                float sn, cs; sincosf(th, &sn, &cs);
                float al = (k == 0) ? (1.f / NP) : (2.f / NP);
                val = al * (comp ? sn : cs);
            }
            o[j] = (_Float16)val;
        }
        *(half8*)&tabI[(size_t)id2 * 8] = o;
    }
}

// ---------------- w_w hi/lo f16 in A-frag order ----------------
__global__ void k_prep_w(const float* __restrict__ ww, _Float16* __restrict__ Wfrag) {
    int idx = blockIdx.x * 256 + threadIdx.x;
    if (idx >= NL * DV * DV) return;
    int l = idx >> 12, cd = idx & 4095, c = cd >> 6, d = cd & 63;
    float wv = ww[((size_t)l * DV + c) * DV + d];     // A[row=d][k=c]
    _Float16 h = (_Float16)wv;
    _Float16 lo = (_Float16)(wv - (float)h);
    int ks = c >> 5, mf = d >> 4;
    int lane = (d & 15) + 16 * ((c >> 3) & 3), j = c & 7;
    Wfrag[((((size_t)l * 2 + 0) * 2 + ks) * 4 + mf) * 512 + (size_t)lane * 8 + j] = h;
    Wfrag[((((size_t)l * 2 + 1) * 2 + ks) * 4 + mf) * 512 + (size_t)lane * 8 + j] = lo;
}

// ---------------- rank-2 layer-0 local coefficients: A0/A1/A2[d] ----------------
__global__ void k_prep_p(const float* __restrict__ pw, const float* __restrict__ pb,
                         const float* __restrict__ ww, float* __restrict__ A) {
    int d = threadIdx.x;
    float a0 = 0.f, a1 = 0.f, a2 = 0.f;
    #pragma unroll 8
    for (int c = 0; c < DV; ++c) {
        float w = ww[(size_t)c * DV + d];   // layer 0
        a0 = fmaf(pw[c], w, a0);
        a1 = fmaf(pw[DV + c], w, a1);
        a2 = fmaf(pb[c], w, a2);
    }
    A[d] = a0; A[64 + d] = a1; A[128 + d] = a2;
}

// ---------------- G[m] = DFT(grid) ----------------
__global__ void k_gd(const float* __restrict__ grd, float* __restrict__ G) {
    __shared__ float rb[256];
    int m = blockIdx.x, k = m >> 1, comp = m & 1;
    int tid = threadIdx.x;
    float s = 0.f;
    for (int t = tid; t < NT; t += 256) {
        int mm = (int)(((long long)t * (long long)k) % NP);
        float th = (float)mm * (PI2 / (float)NP);
        float sn, cs; sincosf(th, &sn, &cs);
        s += grd[t] * (comp ? sn : cs);
    }
    rb[tid] = s; __syncthreads();
    for (int h = 128; h > 0; h >>= 1) { if (tid < h) rb[tid] += rb[tid + h]; __syncthreads(); }
    if (tid == 0) G[m] = rb[0];
}

// ---------------- partial DFT of v (A rows = batch) ----------------
__launch_bounds__(256)
__global__ void k_fdft_v(const float* __restrict__ v, const _Float16* __restrict__ tabF,
                         _Float16* __restrict__ Vp) {
    int ksb = blockIdx.x;
    int tid = threadIdx.x, w = tid >> 6, lane = tid & 63, g = lane >> 4, r = lane & 15;
    const half8* tFv = (const half8*)tabF;
    f32x4 acc[4][2];
    #pragma unroll
    for (int mf = 0; mf < 4; ++mf)
        #pragma unroll
        for (int nf = 0; nf < 2; ++nf) acc[mf][nf] = (f32x4){0.f, 0.f, 0.f, 0.f};
    for (int s = 0; s < SPBV; ++s) {
        int gs = ksb * SPBV + s;
        int t0 = gs * 32 + g * 8;
        half8 a[4];
        #pragma unroll
        for (int mf = 0; mf < 4; ++mf) {
            int brow = mf * 16 + r;
            half8 hv;
            if (t0 < NT) {
                const float4* pv = (const float4*)&v[(size_t)brow * NT + t0];
                float4 v0 = pv[0], v1 = pv[1];
                hv[0] = (_Float16)v0.x; hv[1] = (_Float16)v0.y; hv[2] = (_Float16)v0.z; hv[3] = (_Float16)v0.w;
                hv[4] = (_Float16)v1.x; hv[5] = (_Float16)v1.y; hv[6] = (_Float16)v1.z; hv[7] = (_Float16)v1.w;
            } else {
                #pragma unroll
                for (int j = 0; j < 8; ++j) hv[j] = (_Float16)0.f;
            }
            a[mf] = hv;
        }
        half8 bb[2];
        #pragma unroll
        for (int nf = 0; nf < 2; ++nf) bb[nf] = tFv[((size_t)gs * 8 + w * 2 + nf) * 64 + lane];
        #pragma unroll
        for (int mf = 0; mf < 4; ++mf)
            #pragma unroll
            for (int nf = 0; nf < 2; ++nf)
                acc[mf][nf] = __builtin_amdgcn_mfma_f32_16x16x32_f16(a[mf], bb[nf], acc[mf][nf], 0, 0, 0);
    }
    #pragma unroll
    for (int mf = 0; mf < 4; ++mf)
        #pragma unroll
        for (int nf = 0; nf < 2; ++nf)
            #pragma unroll
            for (int reg = 0; reg < 4; ++reg) {
                int brow = mf * 16 + g * 4 + reg;
                int m = w * 32 + nf * 16 + r;
                Vp[((size_t)ksb * NB + brow) * 128 + m] = (_Float16)acc[mf][nf][reg];
            }
}

// ---------------- spectral mix layer 0 (rank-2 X build) ----------------
__launch_bounds__(256)
__global__ void k_spec0(const _Float16* __restrict__ Vp, const float* __restrict__ G,
                        const float* __restrict__ pw, const float* __restrict__ pb,
                        const float* __restrict__ fw_l, _Float16* __restrict__ zfr) {
    __shared__ float Xs[64][32];
    __shared__ float Vs[32], Gs[32];
    int b = blockIdx.y, kq = blockIdx.x, tid = threadIdx.x;
    if (tid < 32) {
        int m = kq * 32 + tid;
        float ssum = 0.f;
        #pragma unroll
        for (int ks = 0; ks < KSPV; ++ks) ssum += (float)Vp[((size_t)ks * NB + b) * 128 + m];
        Vs[tid] = ssum;
        Gs[tid] = G[m];
    }
    __syncthreads();
    #pragma unroll
    for (int q = 0; q < 8; ++q) {
        int flat = q * 256 + tid;
        int i = flat >> 5, ml = flat & 31;
        float xv = pw[i] * Vs[ml] + pw[64 + i] * Gs[ml];
        if (kq == 0 && ml == 0) xv += pb[i] * (float)NT;
        Xs[i][ml] = xv;
    }
    __syncthreads();
    #pragma unroll
    for (int q = 0; q < 4; ++q) {
        int flat = q * 256 + tid;
        int o = flat >> 4, kl = flat & 15;
        int k = kq * 16 + kl;
        float yr = 0.f, yi = 0.f;
        #pragma unroll 8
        for (int i = 0; i < 64; ++i) {
            float2 xv = *(const float2*)&Xs[i][2 * kl];
            float2 wv = *(const float2*)&fw_l[(((size_t)i * DV + o) * 64 + k) * 2];
            yr = fmaf(xv.x, wv.x, fmaf(xv.y, wv.y, yr));
            yi = fmaf(xv.x, wv.y, fmaf(-xv.y, wv.x, yi));
        }
        int mf = o >> 4, mm = 2 * kl, m1 = mm + 1;
        zfr[((((size_t)b * 4 + kq) * 4 + mf) * 64 + (o & 15) + 16 * (mm >> 3)) * 8 + (mm & 7)] = (_Float16)yr;
        zfr[((((size_t)b * 4 + kq) * 4 + mf) * 64 + (o & 15) + 16 * (m1 >> 3)) * 8 + (m1 & 7)] = (_Float16)(-yi);
    }
}

// ---------------- spectral mix layers 1..3 (frag-ordered partial reduce, 65 partials) ----------------
__launch_bounds__(256)
__global__ void k_spec(const _Float16* __restrict__ xpf, const float* __restrict__ fw_l,
                       _Float16* __restrict__ zfr) {
    __shared__ float Xs[64][32];
    int b = blockIdx.y, kq = blockIdx.x, tid = threadIdx.x;
    float a8[8];
    #pragma unroll
    for (int e = 0; e < 8; ++e) a8[e] = 0.f;
    const half8* src = (const half8*)xpf;
    size_t base8 = ((size_t)b * 4 + kq) * 256 + tid;
    const size_t step8 = (size_t)NB * 4 * 256;
    for (int ks = 0; ks < KSP; ++ks) {
        half8 vv = src[base8 + (size_t)ks * step8];
        #pragma unroll
        for (int e = 0; e < 8; ++e) a8[e] += (float)vv[e];
    }
    int cf = tid >> 6, nf2 = (tid >> 5) & 1, lane0 = (tid & 31) * 2;
    #pragma unroll
    for (int e = 0; e < 8; ++e) {
        int lane = lane0 + (e >> 2), reg = e & 3;
        int g = lane >> 4, r = lane & 15;
        Xs[cf * 16 + g * 4 + reg][nf2 * 16 + r] = a8[e];
    }
    __syncthreads();
    #pragma unroll
    for (int q = 0; q < 4; ++q) {
        int flat = q * 256 + tid;
        int o = flat >> 4, kl = flat & 15;
        int k = kq * 16 + kl;
        float yr = 0.f, yi = 0.f;
        #pragma unroll 8
        for (int i = 0; i < 64; ++i) {
            float2 xv = *(const float2*)&Xs[i][2 * kl];
            float2 wv = *(const float2*)&fw_l[(((size_t)i * DV + o) * 64 + k) * 2];
            yr = fmaf(xv.x, wv.x, fmaf(xv.y, wv.y, yr));
            yi = fmaf(xv.x, wv.y, fmaf(-xv.y, wv.x, yi));
        }
        int mf = o >> 4, mm = 2 * kl, m1 = mm + 1;
        zfr[((((size_t)b * 4 + kq) * 4 + mf) * 64 + (o & 15) + 16 * (mm >> 3)) * 8 + (mm & 7)] = (_Float16)yr;
        zfr[((((size_t)b * 4 + kq) * 4 + mf) * 64 + (o & 15) + 16 * (m1 >> 3)) * 8 + (m1 & 7)] = (_Float16)(-yi);
    }
}

// ---------------- fused: inverse DFT + local + bias + relu + fwd-DFT partials ----------------
// MODE: 0 = FIRST (rank-2 local), 1 = MID, 2 = LAST (q-reduce, no DFT)
// grid (65, NB) for 0/1; (64, NB) for 2. 256 threads = 4 waves, one barrier (0/1 only).
// c-major LDS swizzle: elem (c, tb) at xc[c*128 + (tb ^ (((c>>2)&3)<<3))].
template <int MODE>
__launch_bounds__(256)
__global__ void k_inv(const _Float16* __restrict__ zfr, const _Float16* __restrict__ tabI,
                      const _Float16* __restrict__ tabF, const _Float16* __restrict__ Wl,
                      const float* __restrict__ wb_l, const float* __restrict__ qw,
                      const float* __restrict__ qb, const float* __restrict__ v,
                      const float* __restrict__ grd, const float* __restrict__ A,
                      _Float16* __restrict__ xT, _Float16* __restrict__ xpf,
                      float* __restrict__ out) {
    __shared__ _Float16 xc[64 * 128];    // c-major swizzled block tile, 16 KiB (MODE 0/1)
    __shared__ float Asm[3][64];         // FIRST
    int b = blockIdx.y, bx = blockIdx.x;
    int tid = threadIdx.x, w = tid >> 6, lane = tid & 63;
    int g = lane >> 4, r = lane & 15;
    int tw = bx * 128 + w * 32;
    const half8* zfv = (const half8*)zfr;
    const half8* tIv = (const half8*)tabI;
    const half8* tFv = (const half8*)tabF;
    const half8* wfv = (const half8*)Wl;

    if (MODE == 0) {
        // each wave writes all 192 identical values; own writes precede own reads (lgkmcnt)
        Asm[0][lane] = A[lane];
        Asm[1][lane] = A[64 + lane];
        Asm[2][lane] = A[128 + lane];
    }

    f32x4 acc[4][2];
    #pragma unroll
    for (int mf = 0; mf < 4; ++mf)
        #pragma unroll
        for (int nf = 0; nf < 2; ++nf) acc[mf][nf] = (f32x4){0.f, 0.f, 0.f, 0.f};

    // ---- spectral: A=z, B=tabI ----
    #pragma unroll
    for (int ks4 = 0; ks4 < 4; ++ks4) {
        half8 az[4], bt[2];
        #pragma unroll
        for (int mf = 0; mf < 4; ++mf)
            az[mf] = zfv[(((size_t)b * 4 + ks4) * 4 + mf) * 64 + lane];
        #pragma unroll
        for (int nf = 0; nf < 2; ++nf)
            bt[nf] = tIv[((size_t)ks4 * TFR + (tw >> 4) + nf) * 64 + lane];
        #pragma unroll
        for (int mf = 0; mf < 4; ++mf)
            #pragma unroll
            for (int nf = 0; nf < 2; ++nf)
                acc[mf][nf] = __builtin_amdgcn_mfma_f32_16x16x32_f16(az[mf], bt[nf], acc[mf][nf], 0, 0, 0);
    }
    // ---- local: (Whi + Wlo) * x  (MID/LAST) ----
    if (MODE != 0) {
        half8 xb[2][2];
        #pragma unroll
        for (int ks = 0; ks < 2; ++ks)
            #pragma unroll
            for (int nf = 0; nf < 2; ++nf)
                xb[ks][nf] = *(const half8*)&xT[((size_t)b * NPP + tw + nf * 16 + r) * 64 + ks * 32 + g * 8];
        #pragma unroll
        for (int hl = 0; hl < 2; ++hl)
            #pragma unroll
            for (int ks = 0; ks < 2; ++ks) {
                half8 aw[4];
                #pragma unroll
                for (int mf = 0; mf < 4; ++mf)
                    aw[mf] = wfv[((size_t)(hl * 2 + ks) * 4 + mf) * 64 + lane];
                #pragma unroll
                for (int mf = 0; mf < 4; ++mf)
                    #pragma unroll
                    for (int nf = 0; nf < 2; ++nf)
                        acc[mf][nf] = __builtin_amdgcn_mfma_f32_16x16x32_f16(aw[mf], xb[ks][nf], acc[mf][nf], 0, 0, 0);
            }
    }

    if (MODE != 2) {
        float vv[2], gg[2];
        if (MODE == 0) {
            #pragma unroll
            for (int nf = 0; nf < 2; ++nf) {
                int t = tw + nf * 16 + r;
                bool in = (t < NT);
                vv[nf] = in ? v[(size_t)b * NT + t] : 0.f;
                gg[nf] = in ? grd[t] : 0.f;
            }
        }
        // ---- epilogue: bias(+rank2)+relu -> c-major swizzled LDS (wave-own columns) ----
        #pragma unroll
        for (int mf = 0; mf < 4; ++mf)
            #pragma unroll
            for (int nf = 0; nf < 2; ++nf) {
                int tb = w * 32 + nf * 16 + r;
                #pragma unroll
                for (int reg = 0; reg < 4; ++reg) {
                    int o = mf * 16 + g * 4 + reg;
                    float val = acc[mf][nf][reg] + wb_l[o];
                    if (MODE == 0)
                        val += fmaf(Asm[0][o], vv[nf], fmaf(Asm[1][o], gg[nf], Asm[2][o]));
                    xc[o * 128 + (tb ^ (((o >> 2) & 3) << 3))] = (_Float16)fmaxf(val, 0.f);
                }
            }
        // ---- coalesced xT store from wave-own LDS columns (no barrier needed) ----
        #pragma unroll
        for (int it = 0; it < 4; ++it) {
            int tl = it * 8 + (lane >> 3);       // 0..31 within wave slice
            int tb = w * 32 + tl;
            int c0 = (lane & 7) * 8;
            half8 vv8;
            #pragma unroll
            for (int jj = 0; jj < 8; ++jj) {
                int c = c0 + jj;
                vv8[jj] = xc[c * 128 + (tb ^ (((c >> 2) & 3) << 3))];
            }
            *(half8*)&xT[((size_t)b * NPP + tw + tl) * 64 + c0] = vv8;
        }
        // ---- fwd DFT of this block's fresh x tile -> frag-ordered partial ----
        __syncthreads();
        f32x4 dacc[4][2];
        #pragma unroll
        for (int cf = 0; cf < 4; ++cf)
            #pragma unroll
            for (int nf = 0; nf < 2; ++nf) dacc[cf][nf] = (f32x4){0.f, 0.f, 0.f, 0.f};
        #pragma unroll
        for (int step = 0; step < 4; ++step) {
            int gs = bx * 4 + step;
            half8 a[4], bb[2];
            #pragma unroll
            for (int cf = 0; cf < 4; ++cf) {
                int c = cf * 16 + r;
                a[cf] = *(const half8*)&xc[c * 128 + ((step * 32 + g * 8) ^ (((c >> 2) & 3) << 3))];
            }
            #pragma unroll
            for (int nf = 0; nf < 2; ++nf)
                bb[nf] = tFv[((size_t)gs * 8 + w * 2 + nf) * 64 + lane];
            #pragma unroll
            for (int cf = 0; cf < 4; ++cf)
                #pragma unroll
                for (int nf = 0; nf < 2; ++nf)
                    dacc[cf][nf] = __builtin_amdgcn_mfma_f32_16x16x32_f16(a[cf], bb[nf], dacc[cf][nf], 0, 0, 0);
        }
        _Float16* xp = xpf + (((size_t)bx * NB + b) * 4 + w) * 2048;
        #pragma unroll
        for (int cf = 0; cf < 4; ++cf)
            #pragma unroll
            for (int nf = 0; nf < 2; ++nf) {
                half4 h4;
                #pragma unroll
                for (int reg = 0; reg < 4; ++reg) h4[reg] = (_Float16)dacc[cf][nf][reg];
                *(half4*)&xp[(cf * 2 + nf) * 256 + lane * 4] = h4;
            }
    } else {
        float p0 = 0.f, p1 = 0.f;
        #pragma unroll
        for (int mf = 0; mf < 4; ++mf)
            #pragma unroll
            for (int reg = 0; reg < 4; ++reg) {
                int o = mf * 16 + g * 4 + reg;
                float qq = qw[o], bias = wb_l[o];
                p0 = fmaf(acc[mf][0][reg] + bias, qq, p0);
                p1 = fmaf(acc[mf][1][reg] + bias, qq, p1);
            }
        p0 += __shfl_xor(p0, 16); p0 += __shfl_xor(p0, 32);
        p1 += __shfl_xor(p1, 16); p1 += __shfl_xor(p1, 32);
        float qbv = qb[0];
        if (g == 0) out[(size_t)b * NT + tw + r]      = p0 + qbv;
        if (g == 1) out[(size_t)b * NT + tw + 16 + r] = p1 + qbv;
    }
}

extern "C" void kernel_launch(void* const* d_in, const int* in_sizes, int n_in,
                              void* d_out, int out_size, void* d_ws, size_t ws_size,
                              hipStream_t stream) {
    const float* v   = (const float*)d_in[0];
    const float* grd = (const float*)d_in[1];
    const float* pw  = (const float*)d_in[2];
    const float* pb  = (const float*)d_in[3];
    const float* fw  = (const float*)d_in[4];
    const float* ww  = (const float*)d_in[5];
    const float* wb  = (const float*)d_in[6];
    const float* qw  = (const float*)d_in[7];
    const float* qb  = (const float*)d_in[8];
    float* out = (float*)d_out;

    char* wsb = (char*)d_ws;
    _Float16* xT    = (_Float16*)(wsb + B_XT);
    _Float16* tabFb = (_Float16*)(wsb + B_TABF);
    _Float16* tabIb = (_Float16*)(wsb + B_TABI);
    _Float16* Wfrag = (_Float16*)(wsb + B_WFR);
    _Float16* zfrag = (_Float16*)(wsb + B_ZFR);
    _Float16* xpf   = (_Float16*)(wsb + B_XPF);
    _Float16* Vpart = (_Float16*)(wsb + B_VP);
    float*    G     = (float*)(wsb + B_G);
    float*    A     = (float*)(wsb + B_A);

    k_prep<<<1040, 256, 0, stream>>>(tabFb, tabIb);
    k_prep_w<<<(NL * DV * DV + 255) / 256, 256, 0, stream>>>(ww, Wfrag);
    k_prep_p<<<1, 64, 0, stream>>>(pw, pb, ww, A);
    k_gd<<<128, 256, 0, stream>>>(grd, G);
    k_fdft_v<<<KSPV, 256, 0, stream>>>(v, tabFb, Vpart);

    for (int l = 0; l < NL; ++l) {
        if (l == 0)
            k_spec0<<<dim3(4, NB), 256, 0, stream>>>(Vpart, G, pw, pb, fw, zfrag);
        else
            k_spec<<<dim3(4, NB), 256, 0, stream>>>(xpf, fw + (size_t)l * DV * DV * 64 * 2, zfrag);
        const _Float16* wf_l = Wfrag + (size_t)l * 8192;   // 2*2*4*64*8 per layer
        const float* wb_l = wb + (size_t)l * DV;
        if (l == 0)
            k_inv<0><<<dim3(65, NB), 256, 0, stream>>>(
                zfrag, tabIb, tabFb, wf_l, wb_l, qw, qb, v, grd, A, xT, xpf, out);
        else if (l < NL - 1)
            k_inv<1><<<dim3(65, NB), 256, 0, stream>>>(
                zfrag, tabIb, tabFb, wf_l, wb_l, qw, qb, v, grd, A, xT, xpf, out);
        else
            k_inv<2><<<dim3(64, NB), 256, 0, stream>>>(
                zfrag, tabIb, tabFb, wf_l, wb_l, qw, qb, v, grd, A, xT, xpf, out);
    }
}

// Round 15
// 287.673 us; speedup vs baseline: 1.1966x; 1.1966x over previous
//
#include <hip/hip_runtime.h>

#define NT    8192
#define NP    8200
#define NPP   8320          // 65*128 = 260*32 = 520*16
#define NB    64
#define DV    64
#define NL    4
#define TFR   520
#define KSP   20            // t-splits for standalone fwd-DFT (20*13 = 260 steps)
#define SPB   13
#define PI2   6.28318530717958647692f

typedef _Float16 half8 __attribute__((ext_vector_type(8)));
typedef _Float16 half4 __attribute__((ext_vector_type(4)));
typedef float    f32x4 __attribute__((ext_vector_type(4)));

// ---------------- workspace layout (bytes) ----------------
static const size_t B_XT   = 0;
static const size_t B_TABF = 68157440ull;
static const size_t B_TABI = B_TABF + 2129920ull;
static const size_t B_WFR  = B_TABI + 2129920ull;
static const size_t B_ZFR  = B_WFR  + 131072ull;
static const size_t B_XPF  = B_ZFR  + 1048576ull;
static const size_t B_VP   = B_XPF  + 20971520ull;
static const size_t B_G    = B_VP   + 327680ull;
static const size_t B_A    = B_G    + 512ull;

// ---------------- fused prep: trig tables + Wfrag + A + G in one dispatch ----------------
// blocks 0..1039: tabF/tabI. 1040..1103: Wfrag (16384 elems = 64 blocks). 1104: A. 1105..1232: G.
__global__ void k_prep_all(const float* __restrict__ ww, const float* __restrict__ pw,
                           const float* __restrict__ pb, const float* __restrict__ grd,
                           _Float16* __restrict__ tabF, _Float16* __restrict__ tabI,
                           _Float16* __restrict__ Wfrag, float* __restrict__ A,
                           float* __restrict__ G) {
    int blk = blockIdx.x;
    if (blk < 1040) {
        int idx = blk * 256 + threadIdx.x;
        if (idx < 133120) {                       // tabF: [260 gs][8 cf][64 lane][8 j]
            int lane = idx & 63;
            int rest = idx >> 6;
            int cf = rest & 7, gs = rest >> 3;
            int ml = lane & 15, lh = lane >> 4;
            int m = cf * 16 + ml, k = m >> 1, comp = m & 1;
            half8 o;
            #pragma unroll
            for (int j = 0; j < 8; ++j) {
                int t = gs * 32 + lh * 8 + j;
                float val = 0.f;
                if (t < NP) {
                    int mm = (int)(((long long)t * (long long)k) % NP);
                    float th = (float)mm * (PI2 / (float)NP);
                    float sn, cs; sincosf(th, &sn, &cs);
                    val = comp ? sn : cs;
                }
                o[j] = (_Float16)val;
            }
            *(half8*)&tabF[(size_t)idx * 8] = o;
        } else {                                   // tabI: [4 ks][520 tf][64 lane][8 j]
            int id2 = idx - 133120;
            int lane = id2 & 63;
            int rest = id2 >> 6;
            int tf = rest % 520, ks = rest / 520;
            int lt = lane & 15, mh = lane >> 4;
            int t = tf * 16 + lt;
            half8 o;
            #pragma unroll
            for (int j = 0; j < 8; ++j) {
                int m = ks * 32 + mh * 8 + j;
                int k = m >> 1, comp = m & 1;
                float val = 0.f;
                if (t < NP) {
                    int mm = (int)(((long long)t * (long long)k) % NP);
                    float th = (float)mm * (PI2 / (float)NP);
                    float sn, cs; sincosf(th, &sn, &cs);
                    float al = (k == 0) ? (1.f / NP) : (2.f / NP);
                    val = al * (comp ? sn : cs);
                }
                o[j] = (_Float16)val;
            }
            *(half8*)&tabI[(size_t)id2 * 8] = o;
        }
    } else if (blk < 1104) {                       // Wfrag: 64 blocks x 256 = 16384 elems
        int idx = (blk - 1040) * 256 + threadIdx.x;
        int l = idx >> 12, cd = idx & 4095, c = cd >> 6, d = cd & 63;
        float wv = ww[((size_t)l * DV + c) * DV + d];     // A[row=d][k=c]
        _Float16 h = (_Float16)wv;
        _Float16 lo = (_Float16)(wv - (float)h);
        int ks = c >> 5, mf = d >> 4;
        int lane = (d & 15) + 16 * ((c >> 3) & 3), j = c & 7;
        Wfrag[((((size_t)l * 2 + 0) * 2 + ks) * 4 + mf) * 512 + (size_t)lane * 8 + j] = h;
        Wfrag[((((size_t)l * 2 + 1) * 2 + ks) * 4 + mf) * 512 + (size_t)lane * 8 + j] = lo;
    } else if (blk == 1104) {                      // A0/A1/A2 (layer-0 rank-2 local coeffs)
        int d = threadIdx.x;
        if (d < 64) {
            float a0 = 0.f, a1 = 0.f, a2 = 0.f;
            #pragma unroll 8
            for (int c = 0; c < DV; ++c) {
                float w = ww[(size_t)c * DV + d];   // layer 0
                a0 = fmaf(pw[c], w, a0);
                a1 = fmaf(pw[DV + c], w, a1);
                a2 = fmaf(pb[c], w, a2);
            }
            A[d] = a0; A[64 + d] = a1; A[128 + d] = a2;
        }
    } else {                                       // G[m] = DFT(grid), m = blk-1105
        __shared__ float rb[256];
        int m = blk - 1105, k = m >> 1, comp = m & 1;
        int tid = threadIdx.x;
        float s = 0.f;
        for (int t = tid; t < NT; t += 256) {
            int mm = (int)(((long long)t * (long long)k) % NP);
            float th = (float)mm * (PI2 / (float)NP);
            float sn, cs; sincosf(th, &sn, &cs);
            s += grd[t] * (comp ? sn : cs);
        }
        rb[tid] = s; __syncthreads();
        for (int h = 128; h > 0; h >>= 1) { if (tid < h) rb[tid] += rb[tid + h]; __syncthreads(); }
        if (tid == 0) G[m] = rb[0];
    }
}

// ---------------- partial DFT of v (A rows = batch) ----------------
__launch_bounds__(256)
__global__ void k_fdft_v(const float* __restrict__ v, const _Float16* __restrict__ tabF,
                         _Float16* __restrict__ Vp) {
    int ksb = blockIdx.x;
    int tid = threadIdx.x, w = tid >> 6, lane = tid & 63, g = lane >> 4, r = lane & 15;
    const half8* tFv = (const half8*)tabF;
    f32x4 acc[4][2];
    #pragma unroll
    for (int mf = 0; mf < 4; ++mf)
        #pragma unroll
        for (int nf = 0; nf < 2; ++nf) acc[mf][nf] = (f32x4){0.f, 0.f, 0.f, 0.f};
    for (int s = 0; s < SPB; ++s) {
        int gs = ksb * SPB + s;
        int t0 = gs * 32 + g * 8;
        half8 a[4];
        #pragma unroll
        for (int mf = 0; mf < 4; ++mf) {
            int brow = mf * 16 + r;
            half8 hv;
            if (t0 < NT) {
                const float4* pv = (const float4*)&v[(size_t)brow * NT + t0];
                float4 v0 = pv[0], v1 = pv[1];
                hv[0] = (_Float16)v0.x; hv[1] = (_Float16)v0.y; hv[2] = (_Float16)v0.z; hv[3] = (_Float16)v0.w;
                hv[4] = (_Float16)v1.x; hv[5] = (_Float16)v1.y; hv[6] = (_Float16)v1.z; hv[7] = (_Float16)v1.w;
            } else {
                #pragma unroll
                for (int j = 0; j < 8; ++j) hv[j] = (_Float16)0.f;
            }
            a[mf] = hv;
        }
        half8 bb[2];
        #pragma unroll
        for (int nf = 0; nf < 2; ++nf) bb[nf] = tFv[((size_t)gs * 8 + w * 2 + nf) * 64 + lane];
        #pragma unroll
        for (int mf = 0; mf < 4; ++mf)
            #pragma unroll
            for (int nf = 0; nf < 2; ++nf)
                acc[mf][nf] = __builtin_amdgcn_mfma_f32_16x16x32_f16(a[mf], bb[nf], acc[mf][nf], 0, 0, 0);
    }
    #pragma unroll
    for (int mf = 0; mf < 4; ++mf)
        #pragma unroll
        for (int nf = 0; nf < 2; ++nf)
            #pragma unroll
            for (int reg = 0; reg < 4; ++reg) {
                int brow = mf * 16 + g * 4 + reg;
                int m = w * 32 + nf * 16 + r;
                Vp[((size_t)ksb * NB + brow) * 128 + m] = (_Float16)acc[mf][nf][reg];
            }
}

// ---------------- standalone fwd DFT of xT: double-buffered LDS stage ----------------
__launch_bounds__(256)
__global__ void k_fdft(const _Float16* __restrict__ xT, const _Float16* __restrict__ tabF,
                       _Float16* __restrict__ xpf) {
    __shared__ _Float16 xls[2][2048];   // 2 x [64c][32t] swizzled, 8 KiB
    int sb = blockIdx.x, b = blockIdx.y;
    int tid = threadIdx.x, w = tid >> 6, lane = tid & 63, g = lane >> 4, r = lane & 15;
    const half8* tFv = (const half8*)tabF;
    f32x4 acc[4][2];
    #pragma unroll
    for (int cf = 0; cf < 4; ++cf)
        #pragma unroll
        for (int nf = 0; nf < 2; ++nf) acc[cf][nf] = (f32x4){0.f, 0.f, 0.f, 0.f};
    int tl = tid >> 3, c0 = (tid & 7) * 8;

    half8 vv = *(const half8*)&xT[((size_t)b * NPP + (sb * SPB) * 32 + tl) * 64 + c0];
    #pragma unroll
    for (int j = 0; j < 8; ++j) {
        int c = c0 + j;
        xls[0][c * 32 + (tl ^ (((c >> 3) & 3) << 3))] = vv[j];
    }
    int cur = 0;
    #pragma unroll 1
    for (int s = 0; s < SPB; ++s) {
        int gs = sb * SPB + s;
        half8 vvn;
        if (s + 1 < SPB)
            vvn = *(const half8*)&xT[((size_t)b * NPP + (gs + 1) * 32 + tl) * 64 + c0];
        __syncthreads();
        if (s + 1 < SPB) {
            #pragma unroll
            for (int j = 0; j < 8; ++j) {
                int c = c0 + j;
                xls[cur ^ 1][c * 32 + (tl ^ (((c >> 3) & 3) << 3))] = vvn[j];
            }
        }
        half8 a[4], bb[2];
        #pragma unroll
        for (int cf = 0; cf < 4; ++cf) {
            int c = cf * 16 + r;
            a[cf] = *(const half8*)&xls[cur][c * 32 + ((g * 8) ^ ((((c >> 3) & 3)) << 3))];
        }
        #pragma unroll
        for (int nf = 0; nf < 2; ++nf) bb[nf] = tFv[((size_t)gs * 8 + w * 2 + nf) * 64 + lane];
        #pragma unroll
        for (int cf = 0; cf < 4; ++cf)
            #pragma unroll
            for (int nf = 0; nf < 2; ++nf)
                acc[cf][nf] = __builtin_amdgcn_mfma_f32_16x16x32_f16(a[cf], bb[nf], acc[cf][nf], 0, 0, 0);
        cur ^= 1;
    }
    _Float16* xp = xpf + (((size_t)sb * NB + b) * 4 + w) * 2048;
    #pragma unroll
    for (int cf = 0; cf < 4; ++cf)
        #pragma unroll
        for (int nf = 0; nf < 2; ++nf) {
            half4 h4;
            #pragma unroll
            for (int reg = 0; reg < 4; ++reg) h4[reg] = (_Float16)acc[cf][nf][reg];
            *(half4*)&xp[(cf * 2 + nf) * 256 + lane * 4] = h4;
        }
}

// ---------------- spectral mix layer 0 (rank-2 X build) ----------------
__launch_bounds__(256)
__global__ void k_spec0(const _Float16* __restrict__ Vp, const float* __restrict__ G,
                        const float* __restrict__ pw, const float* __restrict__ pb,
                        const float* __restrict__ fw_l, _Float16* __restrict__ zfr) {
    __shared__ float Xs[64][32];
    __shared__ float Vs[32], Gs[32];
    int b = blockIdx.y, kq = blockIdx.x, tid = threadIdx.x;
    if (tid < 32) {
        int m = kq * 32 + tid;
        float ssum = 0.f;
        #pragma unroll
        for (int ks = 0; ks < KSP; ++ks) ssum += (float)Vp[((size_t)ks * NB + b) * 128 + m];
        Vs[tid] = ssum;
        Gs[tid] = G[m];
    }
    __syncthreads();
    #pragma unroll
    for (int q = 0; q < 8; ++q) {
        int flat = q * 256 + tid;
        int i = flat >> 5, ml = flat & 31;
        float xv = pw[i] * Vs[ml] + pw[64 + i] * Gs[ml];
        if (kq == 0 && ml == 0) xv += pb[i] * (float)NT;
        Xs[i][ml] = xv;
    }
    __syncthreads();
    #pragma unroll
    for (int q = 0; q < 4; ++q) {
        int flat = q * 256 + tid;
        int o = flat >> 4, kl = flat & 15;
        int k = kq * 16 + kl;
        float yr = 0.f, yi = 0.f;
        #pragma unroll 8
        for (int i = 0; i < 64; ++i) {
            float2 xv = *(const float2*)&Xs[i][2 * kl];
            float2 wv = *(const float2*)&fw_l[(((size_t)i * DV + o) * 64 + k) * 2];
            yr = fmaf(xv.x, wv.x, fmaf(xv.y, wv.y, yr));
            yi = fmaf(xv.x, wv.y, fmaf(-xv.y, wv.x, yi));
        }
        int mf = o >> 4, mm = 2 * kl, m1 = mm + 1;
        zfr[((((size_t)b * 4 + kq) * 4 + mf) * 64 + (o & 15) + 16 * (mm >> 3)) * 8 + (mm & 7)] = (_Float16)yr;
        zfr[((((size_t)b * 4 + kq) * 4 + mf) * 64 + (o & 15) + 16 * (m1 >> 3)) * 8 + (m1 & 7)] = (_Float16)(-yi);
    }
}

// ---------------- spectral mix layers 1..3 (frag-ordered partial reduce) ----------------
__launch_bounds__(256)
__global__ void k_spec(const _Float16* __restrict__ xpf, const float* __restrict__ fw_l,
                       _Float16* __restrict__ zfr) {
    __shared__ float Xs[64][32];
    int b = blockIdx.y, kq = blockIdx.x, tid = threadIdx.x;
    float a8[8];
    #pragma unroll
    for (int e = 0; e < 8; ++e) a8[e] = 0.f;
    const half8* src = (const half8*)xpf;
    size_t base8 = ((size_t)b * 4 + kq) * 256 + tid;
    const size_t step8 = (size_t)NB * 4 * 256;
    for (int ks = 0; ks < KSP; ++ks) {
        half8 vv = src[base8 + (size_t)ks * step8];
        #pragma unroll
        for (int e = 0; e < 8; ++e) a8[e] += (float)vv[e];
    }
    int cf = tid >> 6, nf2 = (tid >> 5) & 1, lane0 = (tid & 31) * 2;
    #pragma unroll
    for (int e = 0; e < 8; ++e) {
        int lane = lane0 + (e >> 2), reg = e & 3;
        int g = lane >> 4, r = lane & 15;
        Xs[cf * 16 + g * 4 + reg][nf2 * 16 + r] = a8[e];
    }
    __syncthreads();
    #pragma unroll
    for (int q = 0; q < 4; ++q) {
        int flat = q * 256 + tid;
        int o = flat >> 4, kl = flat & 15;
        int k = kq * 16 + kl;
        float yr = 0.f, yi = 0.f;
        #pragma unroll 8
        for (int i = 0; i < 64; ++i) {
            float2 xv = *(const float2*)&Xs[i][2 * kl];
            float2 wv = *(const float2*)&fw_l[(((size_t)i * DV + o) * 64 + k) * 2];
            yr = fmaf(xv.x, wv.x, fmaf(xv.y, wv.y, yr));
            yi = fmaf(xv.x, wv.y, fmaf(-xv.y, wv.x, yi));
        }
        int mf = o >> 4, mm = 2 * kl, m1 = mm + 1;
        zfr[((((size_t)b * 4 + kq) * 4 + mf) * 64 + (o & 15) + 16 * (mm >> 3)) * 8 + (mm & 7)] = (_Float16)yr;
        zfr[((((size_t)b * 4 + kq) * 4 + mf) * 64 + (o & 15) + 16 * (m1 >> 3)) * 8 + (m1 & 7)] = (_Float16)(-yi);
    }
}

// ---------------- inverse DFT + local + bias (+relu | +q_w reduce), 1-wave blocks ----------------
// MODE: 0 = FIRST (rank-2 local), 1 = MID, 2 = LAST
// grid (260, NB) for 0/1 (wid = blockIdx.x), (256, NB) for 2.
template <int MODE>
__launch_bounds__(64)
__global__ void k_inv(const _Float16* __restrict__ zfr, const _Float16* __restrict__ tabI,
                      const _Float16* __restrict__ Wl, const float* __restrict__ wb_l,
                      const float* __restrict__ qw, const float* __restrict__ qb,
                      const float* __restrict__ v, const float* __restrict__ grd,
                      const float* __restrict__ A,
                      _Float16* __restrict__ xT, float* __restrict__ out) {
    __shared__ _Float16 xw[2048];        // 4 KiB wave-local transpose tile (MODE 0/1)
    __shared__ float Asm[3][64];         // FIRST
    int b = blockIdx.y;
    int wid = blockIdx.x;
    int lane = threadIdx.x;
    int g = lane >> 4, r = lane & 15;
    int tw = wid * 32;
    const half8* zfv = (const half8*)zfr;
    const half8* tIv = (const half8*)tabI;
    const half8* wfv = (const half8*)Wl;

    // ---- hoisted old-x B-frag load (MID/LAST): overlap HBM latency with spectral MFMAs ----
    half8 xb[2][2];
    if (MODE != 0) {
        #pragma unroll
        for (int ks = 0; ks < 2; ++ks)
            #pragma unroll
            for (int nf = 0; nf < 2; ++nf)
                xb[ks][nf] = *(const half8*)&xT[((size_t)b * NPP + tw + nf * 16 + r) * 64 + ks * 32 + g * 8];
    }

    if (MODE == 0) {
        Asm[0][lane] = A[lane];
        Asm[1][lane] = A[64 + lane];
        Asm[2][lane] = A[128 + lane];
    }

    f32x4 acc[4][2];
    #pragma unroll
    for (int mf = 0; mf < 4; ++mf)
        #pragma unroll
        for (int nf = 0; nf < 2; ++nf) acc[mf][nf] = (f32x4){0.f, 0.f, 0.f, 0.f};

    // ---- spectral: A=z, B=tabI ----
    #pragma unroll
    for (int ks4 = 0; ks4 < 4; ++ks4) {
        half8 az[4], bt[2];
        #pragma unroll
        for (int mf = 0; mf < 4; ++mf)
            az[mf] = zfv[(((size_t)b * 4 + ks4) * 4 + mf) * 64 + lane];
        #pragma unroll
        for (int nf = 0; nf < 2; ++nf)
            bt[nf] = tIv[((size_t)ks4 * TFR + (tw >> 4) + nf) * 64 + lane];
        #pragma unroll
        for (int mf = 0; mf < 4; ++mf)
            #pragma unroll
            for (int nf = 0; nf < 2; ++nf)
                acc[mf][nf] = __builtin_amdgcn_mfma_f32_16x16x32_f16(az[mf], bt[nf], acc[mf][nf], 0, 0, 0);
    }
    // ---- local: (Whi + Wlo) * x  (MID/LAST only) ----
    if (MODE != 0) {
        #pragma unroll
        for (int hl = 0; hl < 2; ++hl)
            #pragma unroll
            for (int ks = 0; ks < 2; ++ks) {
                half8 aw[4];
                #pragma unroll
                for (int mf = 0; mf < 4; ++mf)
                    aw[mf] = wfv[((size_t)(hl * 2 + ks) * 4 + mf) * 64 + lane];
                #pragma unroll
                for (int mf = 0; mf < 4; ++mf)
                    #pragma unroll
                    for (int nf = 0; nf < 2; ++nf)
                        acc[mf][nf] = __builtin_amdgcn_mfma_f32_16x16x32_f16(aw[mf], xb[ks][nf], acc[mf][nf], 0, 0, 0);
            }
    }

    if (MODE != 2) {
        float vv[2], gg[2];
        if (MODE == 0) {
            #pragma unroll
            for (int nf = 0; nf < 2; ++nf) {
                int t = tw + nf * 16 + r;
                bool in = (t < NT);
                vv[nf] = in ? v[(size_t)b * NT + t] : 0.f;
                gg[nf] = in ? grd[t] : 0.f;
            }
        }
        // ---- wave-local epilogue: bias(+rank2)+relu -> swizzled LDS -> coalesced store ----
        #pragma unroll
        for (int mf = 0; mf < 4; ++mf)
            #pragma unroll
            for (int nf = 0; nf < 2; ++nf) {
                int tl = nf * 16 + r;
                half4 h4;
                #pragma unroll
                for (int reg = 0; reg < 4; ++reg) {
                    int o = mf * 16 + g * 4 + reg;
                    float val = acc[mf][nf][reg] + wb_l[o];
                    if (MODE == 0)
                        val += fmaf(Asm[0][o], vv[nf], fmaf(Asm[1][o], gg[nf], Asm[2][o]));
                    h4[reg] = (_Float16)fmaxf(val, 0.f);
                }
                int idx = tl * 64 + ((mf * 16 + g * 4) ^ ((tl & 7) << 3));
                *(half4*)&xw[idx] = h4;
            }
        #pragma unroll
        for (int it = 0; it < 4; ++it) {
            int t = it * 8 + (lane >> 3);
            int cg = lane & 7;
            half8 vv8 = *(const half8*)&xw[t * 64 + ((cg * 8) ^ ((t & 7) << 3))];
            *(half8*)&xT[((size_t)b * NPP + tw + t) * 64 + cg * 8] = vv8;
        }
    } else {
        float p0 = 0.f, p1 = 0.f;
        #pragma unroll
        for (int mf = 0; mf < 4; ++mf)
            #pragma unroll
            for (int reg = 0; reg < 4; ++reg) {
                int o = mf * 16 + g * 4 + reg;
                float qq = qw[o], bias = wb_l[o];
                p0 = fmaf(acc[mf][0][reg] + bias, qq, p0);
                p1 = fmaf(acc[mf][1][reg] + bias, qq, p1);
            }
        p0 += __shfl_xor(p0, 16); p0 += __shfl_xor(p0, 32);
        p1 += __shfl_xor(p1, 16); p1 += __shfl_xor(p1, 32);
        float qbv = qb[0];
        if (g == 0) out[(size_t)b * NT + tw + r]      = p0 + qbv;
        if (g == 1) out[(size_t)b * NT + tw + 16 + r] = p1 + qbv;
    }
}

extern "C" void kernel_launch(void* const* d_in, const int* in_sizes, int n_in,
                              void* d_out, int out_size, void* d_ws, size_t ws_size,
                              hipStream_t stream) {
    const float* v   = (const float*)d_in[0];
    const float* grd = (const float*)d_in[1];
    const float* pw  = (const float*)d_in[2];
    const float* pb  = (const float*)d_in[3];
    const float* fw  = (const float*)d_in[4];
    const float* ww  = (const float*)d_in[5];
    const float* wb  = (const float*)d_in[6];
    const float* qw  = (const float*)d_in[7];
    const float* qb  = (const float*)d_in[8];
    float* out = (float*)d_out;

    char* wsb = (char*)d_ws;
    _Float16* xT    = (_Float16*)(wsb + B_XT);
    _Float16* tabFb = (_Float16*)(wsb + B_TABF);
    _Float16* tabIb = (_Float16*)(wsb + B_TABI);
    _Float16* Wfrag = (_Float16*)(wsb + B_WFR);
    _Float16* zfrag = (_Float16*)(wsb + B_ZFR);
    _Float16* xpf   = (_Float16*)(wsb + B_XPF);
    _Float16* Vpart = (_Float16*)(wsb + B_VP);
    float*    G     = (float*)(wsb + B_G);
    float*    A     = (float*)(wsb + B_A);

    k_prep_all<<<1233, 256, 0, stream>>>(ww, pw, pb, grd, tabFb, tabIb, Wfrag, A, G);
    k_fdft_v<<<KSP, 256, 0, stream>>>(v, tabFb, Vpart);

    for (int l = 0; l < NL; ++l) {
        if (l == 0) {
            k_spec0<<<dim3(4, NB), 256, 0, stream>>>(Vpart, G, pw, pb, fw, zfrag);
        } else {
            k_fdft<<<dim3(KSP, NB), 256, 0, stream>>>(xT, tabFb, xpf);
            k_spec<<<dim3(4, NB), 256, 0, stream>>>(xpf, fw + (size_t)l * DV * DV * 64 * 2, zfrag);
        }
        const _Float16* wf_l = Wfrag + (size_t)l * 8192;   // 2*2*4*64*8 per layer
        const float* wb_l = wb + (size_t)l * DV;
        if (l == 0)
            k_inv<0><<<dim3(260, NB), 64, 0, stream>>>(
                zfrag, tabIb, wf_l, wb_l, qw, qb, v, grd, A, xT, out);
        else if (l < NL - 1)
            k_inv<1><<<dim3(260, NB), 64, 0, stream>>>(
                zfrag, tabIb, wf_l, wb_l, qw, qb, v, grd, A, xT, out);
        else
            k_inv<2><<<dim3(256, NB), 64, 0, stream>>>(
                zfrag, tabIb, wf_l, wb_l, qw, qb, v, grd, A, xT, out);
    }
}

// Round 16
// 286.116 us; speedup vs baseline: 1.2031x; 1.0054x over previous
//
#include <hip/hip_runtime.h>

#define NT    8192
#define NP    8200
#define NPP   8320          // 65*128 = 260*32 = 520*16
#define NB    64
#define DV    64
#define NL    4
#define TFR   520
#define KSP   20            // t-splits for standalone fwd-DFT (20*13 = 260 steps)
#define SPB   13
#define PI2   6.28318530717958647692f

typedef _Float16 half8 __attribute__((ext_vector_type(8)));
typedef _Float16 half4 __attribute__((ext_vector_type(4)));
typedef float    f32x4 __attribute__((ext_vector_type(4)));

// ---------------- workspace layout (bytes) ----------------
static const size_t B_XT   = 0;
static const size_t B_TABF = 68157440ull;
static const size_t B_TABI = B_TABF + 2129920ull;
static const size_t B_WFR  = B_TABI + 2129920ull;
static const size_t B_ZFR  = B_WFR  + 131072ull;
static const size_t B_XPF  = B_ZFR  + 1048576ull;
static const size_t B_VP   = B_XPF  + 20971520ull;
static const size_t B_G    = B_VP   + 327680ull;
static const size_t B_A    = B_G    + 512ull;

// ---------------- fused prep: trig tables + Wfrag + A + G in one dispatch ----------------
// blocks 0..1039: tabF/tabI. 1040..1103: Wfrag (16384 elems). 1104: A. 1105..1232: G.
__global__ void k_prep_all(const float* __restrict__ ww, const float* __restrict__ pw,
                           const float* __restrict__ pb, const float* __restrict__ grd,
                           _Float16* __restrict__ tabF, _Float16* __restrict__ tabI,
                           _Float16* __restrict__ Wfrag, float* __restrict__ A,
                           float* __restrict__ G) {
    int blk = blockIdx.x;
    if (blk < 1040) {
        int idx = blk * 256 + threadIdx.x;
        if (idx < 133120) {                       // tabF: [260 gs][8 cf][64 lane][8 j]
            int lane = idx & 63;
            int rest = idx >> 6;
            int cf = rest & 7, gs = rest >> 3;
            int ml = lane & 15, lh = lane >> 4;
            int m = cf * 16 + ml, k = m >> 1, comp = m & 1;
            half8 o;
            #pragma unroll
            for (int j = 0; j < 8; ++j) {
                int t = gs * 32 + lh * 8 + j;
                float val = 0.f;
                if (t < NP) {
                    int mm = (int)(((long long)t * (long long)k) % NP);
                    float th = (float)mm * (PI2 / (float)NP);
                    float sn, cs; sincosf(th, &sn, &cs);
                    val = comp ? sn : cs;
                }
                o[j] = (_Float16)val;
            }
            *(half8*)&tabF[(size_t)idx * 8] = o;
        } else {                                   // tabI: [4 ks][520 tf][64 lane][8 j]
            int id2 = idx - 133120;
            int lane = id2 & 63;
            int rest = id2 >> 6;
            int tf = rest % 520, ks = rest / 520;
            int lt = lane & 15, mh = lane >> 4;
            int t = tf * 16 + lt;
            half8 o;
            #pragma unroll
            for (int j = 0; j < 8; ++j) {
                int m = ks * 32 + mh * 8 + j;
                int k = m >> 1, comp = m & 1;
                float val = 0.f;
                if (t < NP) {
                    int mm = (int)(((long long)t * (long long)k) % NP);
                    float th = (float)mm * (PI2 / (float)NP);
                    float sn, cs; sincosf(th, &sn, &cs);
                    float al = (k == 0) ? (1.f / NP) : (2.f / NP);
                    val = al * (comp ? sn : cs);
                }
                o[j] = (_Float16)val;
            }
            *(half8*)&tabI[(size_t)id2 * 8] = o;
        }
    } else if (blk < 1104) {                       // Wfrag: 64 blocks x 256 = 16384 elems
        int idx = (blk - 1040) * 256 + threadIdx.x;
        int l = idx >> 12, cd = idx & 4095, c = cd >> 6, d = cd & 63;
        float wv = ww[((size_t)l * DV + c) * DV + d];     // A[row=d][k=c]
        _Float16 h = (_Float16)wv;
        _Float16 lo = (_Float16)(wv - (float)h);
        int ks = c >> 5, mf = d >> 4;
        int lane = (d & 15) + 16 * ((c >> 3) & 3), j = c & 7;
        Wfrag[((((size_t)l * 2 + 0) * 2 + ks) * 4 + mf) * 512 + (size_t)lane * 8 + j] = h;
        Wfrag[((((size_t)l * 2 + 1) * 2 + ks) * 4 + mf) * 512 + (size_t)lane * 8 + j] = lo;
    } else if (blk == 1104) {                      // A0/A1/A2 (layer-0 rank-2 local coeffs)
        int d = threadIdx.x;
        if (d < 64) {
            float a0 = 0.f, a1 = 0.f, a2 = 0.f;
            #pragma unroll 8
            for (int c = 0; c < DV; ++c) {
                float w = ww[(size_t)c * DV + d];   // layer 0
                a0 = fmaf(pw[c], w, a0);
                a1 = fmaf(pw[DV + c], w, a1);
                a2 = fmaf(pb[c], w, a2);
            }
            A[d] = a0; A[64 + d] = a1; A[128 + d] = a2;
        }
    } else {                                       // G[m] = DFT(grid), m = blk-1105
        __shared__ float rb[256];
        int m = blk - 1105, k = m >> 1, comp = m & 1;
        int tid = threadIdx.x;
        float s = 0.f;
        for (int t = tid; t < NT; t += 256) {
            int mm = (int)(((long long)t * (long long)k) % NP);
            float th = (float)mm * (PI2 / (float)NP);
            float sn, cs; sincosf(th, &sn, &cs);
            s += grd[t] * (comp ? sn : cs);
        }
        rb[tid] = s; __syncthreads();
        for (int h = 128; h > 0; h >>= 1) { if (tid < h) rb[tid] += rb[tid + h]; __syncthreads(); }
        if (tid == 0) G[m] = rb[0];
    }
}

// ---------------- partial DFT of v (A rows = batch) ----------------
__launch_bounds__(256)
__global__ void k_fdft_v(const float* __restrict__ v, const _Float16* __restrict__ tabF,
                         _Float16* __restrict__ Vp) {
    int ksb = blockIdx.x;
    int tid = threadIdx.x, w = tid >> 6, lane = tid & 63, g = lane >> 4, r = lane & 15;
    const half8* tFv = (const half8*)tabF;
    f32x4 acc[4][2];
    #pragma unroll
    for (int mf = 0; mf < 4; ++mf)
        #pragma unroll
        for (int nf = 0; nf < 2; ++nf) acc[mf][nf] = (f32x4){0.f, 0.f, 0.f, 0.f};
    for (int s = 0; s < SPB; ++s) {
        int gs = ksb * SPB + s;
        int t0 = gs * 32 + g * 8;
        half8 a[4];
        #pragma unroll
        for (int mf = 0; mf < 4; ++mf) {
            int brow = mf * 16 + r;
            half8 hv;
            if (t0 < NT) {
                const float4* pv = (const float4*)&v[(size_t)brow * NT + t0];
                float4 v0 = pv[0], v1 = pv[1];
                hv[0] = (_Float16)v0.x; hv[1] = (_Float16)v0.y; hv[2] = (_Float16)v0.z; hv[3] = (_Float16)v0.w;
                hv[4] = (_Float16)v1.x; hv[5] = (_Float16)v1.y; hv[6] = (_Float16)v1.z; hv[7] = (_Float16)v1.w;
            } else {
                #pragma unroll
                for (int j = 0; j < 8; ++j) hv[j] = (_Float16)0.f;
            }
            a[mf] = hv;
        }
        half8 bb[2];
        #pragma unroll
        for (int nf = 0; nf < 2; ++nf) bb[nf] = tFv[((size_t)gs * 8 + w * 2 + nf) * 64 + lane];
        #pragma unroll
        for (int mf = 0; mf < 4; ++mf)
            #pragma unroll
            for (int nf = 0; nf < 2; ++nf)
                acc[mf][nf] = __builtin_amdgcn_mfma_f32_16x16x32_f16(a[mf], bb[nf], acc[mf][nf], 0, 0, 0);
    }
    #pragma unroll
    for (int mf = 0; mf < 4; ++mf)
        #pragma unroll
        for (int nf = 0; nf < 2; ++nf)
            #pragma unroll
            for (int reg = 0; reg < 4; ++reg) {
                int brow = mf * 16 + g * 4 + reg;
                int m = w * 32 + nf * 16 + r;
                Vp[((size_t)ksb * NB + brow) * 128 + m] = (_Float16)acc[mf][nf][reg];
            }
}

// ---------------- standalone fwd DFT of xT: double-buffered LDS stage ----------------
__launch_bounds__(256)
__global__ void k_fdft(const _Float16* __restrict__ xT, const _Float16* __restrict__ tabF,
                       _Float16* __restrict__ xpf) {
    __shared__ _Float16 xls[2][2048];   // 2 x [64c][32t] swizzled, 8 KiB
    int sb = blockIdx.x, b = blockIdx.y;
    int tid = threadIdx.x, w = tid >> 6, lane = tid & 63, g = lane >> 4, r = lane & 15;
    const half8* tFv = (const half8*)tabF;
    f32x4 acc[4][2];
    #pragma unroll
    for (int cf = 0; cf < 4; ++cf)
        #pragma unroll
        for (int nf = 0; nf < 2; ++nf) acc[cf][nf] = (f32x4){0.f, 0.f, 0.f, 0.f};
    int tl = tid >> 3, c0 = (tid & 7) * 8;

    half8 vv = *(const half8*)&xT[((size_t)b * NPP + (sb * SPB) * 32 + tl) * 64 + c0];
    #pragma unroll
    for (int j = 0; j < 8; ++j) {
        int c = c0 + j;
        xls[0][c * 32 + (tl ^ (((c >> 3) & 3) << 3))] = vv[j];
    }
    int cur = 0;
    #pragma unroll 1
    for (int s = 0; s < SPB; ++s) {
        int gs = sb * SPB + s;
        half8 vvn;
        if (s + 1 < SPB)
            vvn = *(const half8*)&xT[((size_t)b * NPP + (gs + 1) * 32 + tl) * 64 + c0];
        __syncthreads();
        if (s + 1 < SPB) {
            #pragma unroll
            for (int j = 0; j < 8; ++j) {
                int c = c0 + j;
                xls[cur ^ 1][c * 32 + (tl ^ (((c >> 3) & 3) << 3))] = vvn[j];
            }
        }
        half8 a[4], bb[2];
        #pragma unroll
        for (int cf = 0; cf < 4; ++cf) {
            int c = cf * 16 + r;
            a[cf] = *(const half8*)&xls[cur][c * 32 + ((g * 8) ^ ((((c >> 3) & 3)) << 3))];
        }
        #pragma unroll
        for (int nf = 0; nf < 2; ++nf) bb[nf] = tFv[((size_t)gs * 8 + w * 2 + nf) * 64 + lane];
        #pragma unroll
        for (int cf = 0; cf < 4; ++cf)
            #pragma unroll
            for (int nf = 0; nf < 2; ++nf)
                acc[cf][nf] = __builtin_amdgcn_mfma_f32_16x16x32_f16(a[cf], bb[nf], acc[cf][nf], 0, 0, 0);
        cur ^= 1;
    }
    _Float16* xp = xpf + (((size_t)sb * NB + b) * 4 + w) * 2048;
    #pragma unroll
    for (int cf = 0; cf < 4; ++cf)
        #pragma unroll
        for (int nf = 0; nf < 2; ++nf) {
            half4 h4;
            #pragma unroll
            for (int reg = 0; reg < 4; ++reg) h4[reg] = (_Float16)acc[cf][nf][reg];
            *(half4*)&xp[(cf * 2 + nf) * 256 + lane * 4] = h4;
        }
}

// ---------------- spectral mix layer 0 (rank-2 X build) ----------------
__launch_bounds__(256)
__global__ void k_spec0(const _Float16* __restrict__ Vp, const float* __restrict__ G,
                        const float* __restrict__ pw, const float* __restrict__ pb,
                        const float* __restrict__ fw_l, _Float16* __restrict__ zfr) {
    __shared__ float Xs[64][32];
    __shared__ float Vs[32], Gs[32];
    int b = blockIdx.y, kq = blockIdx.x, tid = threadIdx.x;
    if (tid < 32) {
        int m = kq * 32 + tid;
        float ssum = 0.f;
        #pragma unroll
        for (int ks = 0; ks < KSP; ++ks) ssum += (float)Vp[((size_t)ks * NB + b) * 128 + m];
        Vs[tid] = ssum;
        Gs[tid] = G[m];
    }
    __syncthreads();
    #pragma unroll
    for (int q = 0; q < 8; ++q) {
        int flat = q * 256 + tid;
        int i = flat >> 5, ml = flat & 31;
        float xv = pw[i] * Vs[ml] + pw[64 + i] * Gs[ml];
        if (kq == 0 && ml == 0) xv += pb[i] * (float)NT;
        Xs[i][ml] = xv;
    }
    __syncthreads();
    #pragma unroll
    for (int q = 0; q < 4; ++q) {
        int flat = q * 256 + tid;
        int o = flat >> 4, kl = flat & 15;
        int k = kq * 16 + kl;
        float yr = 0.f, yi = 0.f;
        #pragma unroll 8
        for (int i = 0; i < 64; ++i) {
            float2 xv = *(const float2*)&Xs[i][2 * kl];
            float2 wv = *(const float2*)&fw_l[(((size_t)i * DV + o) * 64 + k) * 2];
            yr = fmaf(xv.x, wv.x, fmaf(xv.y, wv.y, yr));
            yi = fmaf(xv.x, wv.y, fmaf(-xv.y, wv.x, yi));
        }
        int mf = o >> 4, mm = 2 * kl, m1 = mm + 1;
        zfr[((((size_t)b * 4 + kq) * 4 + mf) * 64 + (o & 15) + 16 * (mm >> 3)) * 8 + (mm & 7)] = (_Float16)yr;
        zfr[((((size_t)b * 4 + kq) * 4 + mf) * 64 + (o & 15) + 16 * (m1 >> 3)) * 8 + (m1 & 7)] = (_Float16)(-yi);
    }
}

// ---------------- spectral mix layers 1..3 (frag-ordered partial reduce) ----------------
__launch_bounds__(256)
__global__ void k_spec(const _Float16* __restrict__ xpf, const float* __restrict__ fw_l,
                       _Float16* __restrict__ zfr) {
    __shared__ float Xs[64][32];
    int b = blockIdx.y, kq = blockIdx.x, tid = threadIdx.x;
    float a8[8];
    #pragma unroll
    for (int e = 0; e < 8; ++e) a8[e] = 0.f;
    const half8* src = (const half8*)xpf;
    size_t base8 = ((size_t)b * 4 + kq) * 256 + tid;
    const size_t step8 = (size_t)NB * 4 * 256;
    for (int ks = 0; ks < KSP; ++ks) {
        half8 vv = src[base8 + (size_t)ks * step8];
        #pragma unroll
        for (int e = 0; e < 8; ++e) a8[e] += (float)vv[e];
    }
    int cf = tid >> 6, nf2 = (tid >> 5) & 1, lane0 = (tid & 31) * 2;
    #pragma unroll
    for (int e = 0; e < 8; ++e) {
        int lane = lane0 + (e >> 2), reg = e & 3;
        int g = lane >> 4, r = lane & 15;
        Xs[cf * 16 + g * 4 + reg][nf2 * 16 + r] = a8[e];
    }
    __syncthreads();
    #pragma unroll
    for (int q = 0; q < 4; ++q) {
        int flat = q * 256 + tid;
        int o = flat >> 4, kl = flat & 15;
        int k = kq * 16 + kl;
        float yr = 0.f, yi = 0.f;
        #pragma unroll 8
        for (int i = 0; i < 64; ++i) {
            float2 xv = *(const float2*)&Xs[i][2 * kl];
            float2 wv = *(const float2*)&fw_l[(((size_t)i * DV + o) * 64 + k) * 2];
            yr = fmaf(xv.x, wv.x, fmaf(xv.y, wv.y, yr));
            yi = fmaf(xv.x, wv.y, fmaf(-xv.y, wv.x, yi));
        }
        int mf = o >> 4, mm = 2 * kl, m1 = mm + 1;
        zfr[((((size_t)b * 4 + kq) * 4 + mf) * 64 + (o & 15) + 16 * (mm >> 3)) * 8 + (mm & 7)] = (_Float16)yr;
        zfr[((((size_t)b * 4 + kq) * 4 + mf) * 64 + (o & 15) + 16 * (m1 >> 3)) * 8 + (m1 & 7)] = (_Float16)(-yi);
    }
}

// ---------------- inverse DFT + local + bias (+relu | +q_w reduce), 2 tiles/wave ----------------
// MODE: 0 = FIRST (rank-2 local), 1 = MID, 2 = LAST
// grid (130, NB) for 0/1 (wave owns t in [wid*64, wid*64+64)), (128, NB) for 2.
template <int MODE>
__launch_bounds__(64)
__global__ void k_inv(const _Float16* __restrict__ zfr, const _Float16* __restrict__ tabI,
                      const _Float16* __restrict__ Wl, const float* __restrict__ wb_l,
                      const float* __restrict__ qw, const float* __restrict__ qb,
                      const float* __restrict__ v, const float* __restrict__ grd,
                      const float* __restrict__ A,
                      _Float16* __restrict__ xT, float* __restrict__ out) {
    __shared__ _Float16 xw[2048];        // 4 KiB wave-local transpose tile, reused per sub-tile
    __shared__ float Asm[3][64];         // FIRST
    int b = blockIdx.y;
    int wid = blockIdx.x;
    int lane = threadIdx.x;
    int g = lane >> 4, r = lane & 15;
    int tw0 = wid * 64;
    const half8* zfv = (const half8*)zfr;
    const half8* tIv = (const half8*)tabI;
    const half8* wfv = (const half8*)Wl;

    // ---- hoisted old-x B-frag load, tile 0 (MID/LAST) ----
    half8 xb0[2][2];
    if (MODE != 0) {
        #pragma unroll
        for (int ks = 0; ks < 2; ++ks)
            #pragma unroll
            for (int nf = 0; nf < 2; ++nf)
                xb0[ks][nf] = *(const half8*)&xT[((size_t)b * NPP + tw0 + nf * 16 + r) * 64 + ks * 32 + g * 8];
    }
    if (MODE == 0) {
        Asm[0][lane] = A[lane];
        Asm[1][lane] = A[64 + lane];
        Asm[2][lane] = A[128 + lane];
    }

    f32x4 acc[2][4][2];
    #pragma unroll
    for (int tt = 0; tt < 2; ++tt)
        #pragma unroll
        for (int mf = 0; mf < 4; ++mf)
            #pragma unroll
            for (int nf = 0; nf < 2; ++nf) acc[tt][mf][nf] = (f32x4){0.f, 0.f, 0.f, 0.f};

    // ---- spectral: A=z (shared across both tiles), B=tabI ----
    #pragma unroll
    for (int ks4 = 0; ks4 < 4; ++ks4) {
        half8 az[4], bt0[2], bt1[2];
        #pragma unroll
        for (int mf = 0; mf < 4; ++mf)
            az[mf] = zfv[(((size_t)b * 4 + ks4) * 4 + mf) * 64 + lane];
        #pragma unroll
        for (int nf = 0; nf < 2; ++nf) {
            bt0[nf] = tIv[((size_t)ks4 * TFR + (tw0 >> 4) + nf) * 64 + lane];
            bt1[nf] = tIv[((size_t)ks4 * TFR + (tw0 >> 4) + 2 + nf) * 64 + lane];
        }
        #pragma unroll
        for (int mf = 0; mf < 4; ++mf)
            #pragma unroll
            for (int nf = 0; nf < 2; ++nf) {
                acc[0][mf][nf] = __builtin_amdgcn_mfma_f32_16x16x32_f16(az[mf], bt0[nf], acc[0][mf][nf], 0, 0, 0);
                acc[1][mf][nf] = __builtin_amdgcn_mfma_f32_16x16x32_f16(az[mf], bt1[nf], acc[1][mf][nf], 0, 0, 0);
            }
    }
    // ---- local: (Whi + Wlo) * x  (MID/LAST only), tile-by-tile ----
    half8 xb1[2][2];
    if (MODE != 0) {
        #pragma unroll
        for (int ks = 0; ks < 2; ++ks)
            #pragma unroll
            for (int nf = 0; nf < 2; ++nf)
                xb1[ks][nf] = *(const half8*)&xT[((size_t)b * NPP + tw0 + 32 + nf * 16 + r) * 64 + ks * 32 + g * 8];
        #pragma unroll
        for (int hl = 0; hl < 2; ++hl)
            #pragma unroll
            for (int ks = 0; ks < 2; ++ks) {
                half8 aw[4];
                #pragma unroll
                for (int mf = 0; mf < 4; ++mf)
                    aw[mf] = wfv[((size_t)(hl * 2 + ks) * 4 + mf) * 64 + lane];
                #pragma unroll
                for (int mf = 0; mf < 4; ++mf)
                    #pragma unroll
                    for (int nf = 0; nf < 2; ++nf) {
                        acc[0][mf][nf] = __builtin_amdgcn_mfma_f32_16x16x32_f16(aw[mf], xb0[ks][nf], acc[0][mf][nf], 0, 0, 0);
                        acc[1][mf][nf] = __builtin_amdgcn_mfma_f32_16x16x32_f16(aw[mf], xb1[ks][nf], acc[1][mf][nf], 0, 0, 0);
                    }
            }
    }

    if (MODE != 2) {
        #pragma unroll
        for (int tt = 0; tt < 2; ++tt) {
            int tw = tw0 + tt * 32;
            float vv[2], gg[2];
            if (MODE == 0) {
                #pragma unroll
                for (int nf = 0; nf < 2; ++nf) {
                    int t = tw + nf * 16 + r;
                    bool in = (t < NT);
                    vv[nf] = in ? v[(size_t)b * NT + t] : 0.f;
                    gg[nf] = in ? grd[t] : 0.f;
                }
            }
            // ---- wave-local epilogue: bias(+rank2)+relu -> swizzled LDS -> coalesced store ----
            #pragma unroll
            for (int mf = 0; mf < 4; ++mf)
                #pragma unroll
                for (int nf = 0; nf < 2; ++nf) {
                    int tl = nf * 16 + r;
                    half4 h4;
                    #pragma unroll
                    for (int reg = 0; reg < 4; ++reg) {
                        int o = mf * 16 + g * 4 + reg;
                        float val = acc[tt][mf][nf][reg] + wb_l[o];
                        if (MODE == 0)
                            val += fmaf(Asm[0][o], vv[nf], fmaf(Asm[1][o], gg[nf], Asm[2][o]));
                        h4[reg] = (_Float16)fmaxf(val, 0.f);
                    }
                    int idx = tl * 64 + ((mf * 16 + g * 4) ^ ((tl & 7) << 3));
                    *(half4*)&xw[idx] = h4;
                }
            #pragma unroll
            for (int it = 0; it < 4; ++it) {
                int t = it * 8 + (lane >> 3);
                int cg = lane & 7;
                half8 vv8 = *(const half8*)&xw[t * 64 + ((cg * 8) ^ ((t & 7) << 3))];
                *(half8*)&xT[((size_t)b * NPP + tw + t) * 64 + cg * 8] = vv8;
            }
        }
    } else {
        float qbv = qb[0];
        #pragma unroll
        for (int tt = 0; tt < 2; ++tt) {
            int tw = tw0 + tt * 32;
            float p0 = 0.f, p1 = 0.f;
            #pragma unroll
            for (int mf = 0; mf < 4; ++mf)
                #pragma unroll
                for (int reg = 0; reg < 4; ++reg) {
                    int o = mf * 16 + g * 4 + reg;
                    float qq = qw[o], bias = wb_l[o];
                    p0 = fmaf(acc[tt][mf][0][reg] + bias, qq, p0);
                    p1 = fmaf(acc[tt][mf][1][reg] + bias, qq, p1);
                }
            p0 += __shfl_xor(p0, 16); p0 += __shfl_xor(p0, 32);
            p1 += __shfl_xor(p1, 16); p1 += __shfl_xor(p1, 32);
            if (g == 0) out[(size_t)b * NT + tw + r]      = p0 + qbv;
            if (g == 1) out[(size_t)b * NT + tw + 16 + r] = p1 + qbv;
        }
    }
}

extern "C" void kernel_launch(void* const* d_in, const int* in_sizes, int n_in,
                              void* d_out, int out_size, void* d_ws, size_t ws_size,
                              hipStream_t stream) {
    const float* v   = (const float*)d_in[0];
    const float* grd = (const float*)d_in[1];
    const float* pw  = (const float*)d_in[2];
    const float* pb  = (const float*)d_in[3];
    const float* fw  = (const float*)d_in[4];
    const float* ww  = (const float*)d_in[5];
    const float* wb  = (const float*)d_in[6];
    const float* qw  = (const float*)d_in[7];
    const float* qb  = (const float*)d_in[8];
    float* out = (float*)d_out;

    char* wsb = (char*)d_ws;
    _Float16* xT    = (_Float16*)(wsb + B_XT);
    _Float16* tabFb = (_Float16*)(wsb + B_TABF);
    _Float16* tabIb = (_Float16*)(wsb + B_TABI);
    _Float16* Wfrag = (_Float16*)(wsb + B_WFR);
    _Float16* zfrag = (_Float16*)(wsb + B_ZFR);
    _Float16* xpf   = (_Float16*)(wsb + B_XPF);
    _Float16* Vpart = (_Float16*)(wsb + B_VP);
    float*    G     = (float*)(wsb + B_G);
    float*    A     = (float*)(wsb + B_A);

    k_prep_all<<<1233, 256, 0, stream>>>(ww, pw, pb, grd, tabFb, tabIb, Wfrag, A, G);
    k_fdft_v<<<KSP, 256, 0, stream>>>(v, tabFb, Vpart);

    for (int l = 0; l < NL; ++l) {
        if (l == 0) {
            k_spec0<<<dim3(4, NB), 256, 0, stream>>>(Vpart, G, pw, pb, fw, zfrag);
        } else {
            k_fdft<<<dim3(KSP, NB), 256, 0, stream>>>(xT, tabFb, xpf);
            k_spec<<<dim3(4, NB), 256, 0, stream>>>(xpf, fw + (size_t)l * DV * DV * 64 * 2, zfrag);
        }
        const _Float16* wf_l = Wfrag + (size_t)l * 8192;   // 2*2*4*64*8 per layer
        const float* wb_l = wb + (size_t)l * DV;
        if (l == 0)
            k_inv<0><<<dim3(130, NB), 64, 0, stream>>>(
                zfrag, tabIb, wf_l, wb_l, qw, qb, v, grd, A, xT, out);
        else if (l < NL - 1)
            k_inv<1><<<dim3(130, NB), 64, 0, stream>>>(
                zfrag, tabIb, wf_l, wb_l, qw, qb, v, grd, A, xT, out);
        else
            k_inv<2><<<dim3(128, NB), 64, 0, stream>>>(
                zfrag, tabIb, wf_l, wb_l, qw, qb, v, grd, A, xT, out);
    }
}

// Round 17
// 285.647 us; speedup vs baseline: 1.2051x; 1.0016x over previous
//
#include <hip/hip_runtime.h>

#define NT    8192
#define NP    8200
#define NPP   8320          // 65*128 = 260*32 = 520*16
#define NB    64
#define DV    64
#define NL    4
#define TFR   520
#define KSP   20            // t-splits for standalone fwd-DFT (20*13 = 260 steps)
#define SPB   13
#define PI2   6.28318530717958647692f

typedef _Float16 half8 __attribute__((ext_vector_type(8)));
typedef _Float16 half4 __attribute__((ext_vector_type(4)));
typedef float    f32x4 __attribute__((ext_vector_type(4)));

// ---------------- workspace layout (bytes) ----------------
static const size_t B_XT   = 0;
static const size_t B_TABF = 68157440ull;
static const size_t B_TABI = B_TABF + 2129920ull;
static const size_t B_WFR  = B_TABI + 2129920ull;
static const size_t B_ZFR  = B_WFR  + 131072ull;
static const size_t B_XPF  = B_ZFR  + 1048576ull;
static const size_t B_VP   = B_XPF  + 20971520ull;
static const size_t B_G    = B_VP   + 327680ull;
static const size_t B_A    = B_G    + 512ull;

// ---------------- fused prep: trig (single pass -> both tables) + Wfrag + A + G ----------------
// blocks 0..519: tabF coalesced + tabI scattered. 520..583: Wfrag. 584: A. 585..712: G.
__global__ void k_prep_all(const float* __restrict__ ww, const float* __restrict__ pw,
                           const float* __restrict__ pb, const float* __restrict__ grd,
                           _Float16* __restrict__ tabF, _Float16* __restrict__ tabI,
                           _Float16* __restrict__ Wfrag, float* __restrict__ A,
                           float* __restrict__ G) {
    int blk = blockIdx.x;
    if (blk < 520) {
        int idx = blk * 256 + threadIdx.x;        // 133120 threads: tabF [260 gs][8 cf][64 lane]
        int lane = idx & 63;
        int rest = idx >> 6;
        int cf = rest & 7, gs = rest >> 3;
        int ml = lane & 15, lh = lane >> 4;
        int m = cf * 16 + ml, k = m >> 1, comp = m & 1;
        float al = (k == 0) ? (1.f / NP) : (2.f / NP);
        // tabI constant sub-index for this thread's m
        size_t ti_m = ((size_t)(m >> 5) * TFR) * 512 + (size_t)(16 * ((m >> 3) & 3)) * 8 + (m & 7);
        half8 o;
        #pragma unroll
        for (int j = 0; j < 8; ++j) {
            int t = gs * 32 + lh * 8 + j;
            float val = 0.f;
            if (t < NP) {
                int mm = (int)(((long long)t * (long long)k) % NP);
                float th = (float)mm * (PI2 / (float)NP);
                float sn, cs; sincosf(th, &sn, &cs);
                val = comp ? sn : cs;
            }
            o[j] = (_Float16)val;
            // tabI[(m>>5)*TFR + (t>>4)][ (t&15) + 16*((m>>3)&3) ][ m&7 ]
            tabI[ti_m + (size_t)(t >> 4) * 512 + (size_t)(t & 15) * 8] = (_Float16)(al * val);
        }
        *(half8*)&tabF[(size_t)idx * 8] = o;
    } else if (blk < 584) {                       // Wfrag: 64 blocks x 256 = 16384 elems
        int idx = (blk - 520) * 256 + threadIdx.x;
        int l = idx >> 12, cd = idx & 4095, c = cd >> 6, d = cd & 63;
        float wv = ww[((size_t)l * DV + c) * DV + d];     // A[row=d][k=c]
        _Float16 h = (_Float16)wv;
        _Float16 lo = (_Float16)(wv - (float)h);
        int ks = c >> 5, mf = d >> 4;
        int lane = (d & 15) + 16 * ((c >> 3) & 3), j = c & 7;
        Wfrag[((((size_t)l * 2 + 0) * 2 + ks) * 4 + mf) * 512 + (size_t)lane * 8 + j] = h;
        Wfrag[((((size_t)l * 2 + 1) * 2 + ks) * 4 + mf) * 512 + (size_t)lane * 8 + j] = lo;
    } else if (blk == 584) {                      // A0/A1/A2 (layer-0 rank-2 local coeffs)
        int d = threadIdx.x;
        if (d < 64) {
            float a0 = 0.f, a1 = 0.f, a2 = 0.f;
            #pragma unroll 8
            for (int c = 0; c < DV; ++c) {
                float w = ww[(size_t)c * DV + d];   // layer 0
                a0 = fmaf(pw[c], w, a0);
                a1 = fmaf(pw[DV + c], w, a1);
                a2 = fmaf(pb[c], w, a2);
            }
            A[d] = a0; A[64 + d] = a1; A[128 + d] = a2;
        }
    } else {                                       // G[m] = DFT(grid), m = blk-585
        __shared__ float rb[256];
        int m = blk - 585, k = m >> 1, comp = m & 1;
        int tid = threadIdx.x;
        float s = 0.f;
        for (int t = tid; t < NT; t += 256) {
            int mm = (int)(((long long)t * (long long)k) % NP);
            float th = (float)mm * (PI2 / (float)NP);
            float sn, cs; sincosf(th, &sn, &cs);
            s += grd[t] * (comp ? sn : cs);
        }
        rb[tid] = s; __syncthreads();
        for (int h = 128; h > 0; h >>= 1) { if (tid < h) rb[tid] += rb[tid + h]; __syncthreads(); }
        if (tid == 0) G[m] = rb[0];
    }
}

// ---------------- partial DFT of v (A rows = batch) ----------------
__launch_bounds__(256)
__global__ void k_fdft_v(const float* __restrict__ v, const _Float16* __restrict__ tabF,
                         _Float16* __restrict__ Vp) {
    int ksb = blockIdx.x;
    int tid = threadIdx.x, w = tid >> 6, lane = tid & 63, g = lane >> 4, r = lane & 15;
    const half8* tFv = (const half8*)tabF;
    f32x4 acc[4][2];
    #pragma unroll
    for (int mf = 0; mf < 4; ++mf)
        #pragma unroll
        for (int nf = 0; nf < 2; ++nf) acc[mf][nf] = (f32x4){0.f, 0.f, 0.f, 0.f};
    for (int s = 0; s < SPB; ++s) {
        int gs = ksb * SPB + s;
        int t0 = gs * 32 + g * 8;
        half8 a[4];
        #pragma unroll
        for (int mf = 0; mf < 4; ++mf) {
            int brow = mf * 16 + r;
            half8 hv;
            if (t0 < NT) {
                const float4* pv = (const float4*)&v[(size_t)brow * NT + t0];
                float4 v0 = pv[0], v1 = pv[1];
                hv[0] = (_Float16)v0.x; hv[1] = (_Float16)v0.y; hv[2] = (_Float16)v0.z; hv[3] = (_Float16)v0.w;
                hv[4] = (_Float16)v1.x; hv[5] = (_Float16)v1.y; hv[6] = (_Float16)v1.z; hv[7] = (_Float16)v1.w;
            } else {
                #pragma unroll
                for (int j = 0; j < 8; ++j) hv[j] = (_Float16)0.f;
            }
            a[mf] = hv;
        }
        half8 bb[2];
        #pragma unroll
        for (int nf = 0; nf < 2; ++nf) bb[nf] = tFv[((size_t)gs * 8 + w * 2 + nf) * 64 + lane];
        #pragma unroll
        for (int mf = 0; mf < 4; ++mf)
            #pragma unroll
            for (int nf = 0; nf < 2; ++nf)
                acc[mf][nf] = __builtin_amdgcn_mfma_f32_16x16x32_f16(a[mf], bb[nf], acc[mf][nf], 0, 0, 0);
    }
    #pragma unroll
    for (int mf = 0; mf < 4; ++mf)
        #pragma unroll
        for (int nf = 0; nf < 2; ++nf)
            #pragma unroll
            for (int reg = 0; reg < 4; ++reg) {
                int brow = mf * 16 + g * 4 + reg;
                int m = w * 32 + nf * 16 + r;
                Vp[((size_t)ksb * NB + brow) * 128 + m] = (_Float16)acc[mf][nf][reg];
            }
}

// ---------------- standalone fwd DFT of xT: double-buffered LDS stage ----------------
__launch_bounds__(256)
__global__ void k_fdft(const _Float16* __restrict__ xT, const _Float16* __restrict__ tabF,
                       _Float16* __restrict__ xpf) {
    __shared__ _Float16 xls[2][2048];   // 2 x [64c][32t] swizzled, 8 KiB
    int sb = blockIdx.x, b = blockIdx.y;
    int tid = threadIdx.x, w = tid >> 6, lane = tid & 63, g = lane >> 4, r = lane & 15;
    const half8* tFv = (const half8*)tabF;
    f32x4 acc[4][2];
    #pragma unroll
    for (int cf = 0; cf < 4; ++cf)
        #pragma unroll
        for (int nf = 0; nf < 2; ++nf) acc[cf][nf] = (f32x4){0.f, 0.f, 0.f, 0.f};
    int tl = tid >> 3, c0 = (tid & 7) * 8;

    half8 vv = *(const half8*)&xT[((size_t)b * NPP + (sb * SPB) * 32 + tl) * 64 + c0];
    #pragma unroll
    for (int j = 0; j < 8; ++j) {
        int c = c0 + j;
        xls[0][c * 32 + (tl ^ (((c >> 3) & 3) << 3))] = vv[j];
    }
    int cur = 0;
    #pragma unroll 1
    for (int s = 0; s < SPB; ++s) {
        int gs = sb * SPB + s;
        half8 vvn;
        if (s + 1 < SPB)
            vvn = *(const half8*)&xT[((size_t)b * NPP + (gs + 1) * 32 + tl) * 64 + c0];
        __syncthreads();
        if (s + 1 < SPB) {
            #pragma unroll
            for (int j = 0; j < 8; ++j) {
                int c = c0 + j;
                xls[cur ^ 1][c * 32 + (tl ^ (((c >> 3) & 3) << 3))] = vvn[j];
            }
        }
        half8 a[4], bb[2];
        #pragma unroll
        for (int cf = 0; cf < 4; ++cf) {
            int c = cf * 16 + r;
            a[cf] = *(const half8*)&xls[cur][c * 32 + ((g * 8) ^ ((((c >> 3) & 3)) << 3))];
        }
        #pragma unroll
        for (int nf = 0; nf < 2; ++nf) bb[nf] = tFv[((size_t)gs * 8 + w * 2 + nf) * 64 + lane];
        #pragma unroll
        for (int cf = 0; cf < 4; ++cf)
            #pragma unroll
            for (int nf = 0; nf < 2; ++nf)
                acc[cf][nf] = __builtin_amdgcn_mfma_f32_16x16x32_f16(a[cf], bb[nf], acc[cf][nf], 0, 0, 0);
        cur ^= 1;
    }
    _Float16* xp = xpf + (((size_t)sb * NB + b) * 4 + w) * 2048;
    #pragma unroll
    for (int cf = 0; cf < 4; ++cf)
        #pragma unroll
        for (int nf = 0; nf < 2; ++nf) {
            half4 h4;
            #pragma unroll
            for (int reg = 0; reg < 4; ++reg) h4[reg] = (_Float16)acc[cf][nf][reg];
            *(half4*)&xp[(cf * 2 + nf) * 256 + lane * 4] = h4;
        }
}

// ---------------- spectral mix layer 0 (rank-2 X build) ----------------
__launch_bounds__(256)
__global__ void k_spec0(const _Float16* __restrict__ Vp, const float* __restrict__ G,
                        const float* __restrict__ pw, const float* __restrict__ pb,
                        const float* __restrict__ fw_l, _Float16* __restrict__ zfr) {
    __shared__ float Xs[64][32];
    __shared__ float Vs[32], Gs[32];
    int b = blockIdx.y, kq = blockIdx.x, tid = threadIdx.x;
    if (tid < 32) {
        int m = kq * 32 + tid;
        float ssum = 0.f;
        #pragma unroll
        for (int ks = 0; ks < KSP; ++ks) ssum += (float)Vp[((size_t)ks * NB + b) * 128 + m];
        Vs[tid] = ssum;
        Gs[tid] = G[m];
    }
    __syncthreads();
    #pragma unroll
    for (int q = 0; q < 8; ++q) {
        int flat = q * 256 + tid;
        int i = flat >> 5, ml = flat & 31;
        float xv = pw[i] * Vs[ml] + pw[64 + i] * Gs[ml];
        if (kq == 0 && ml == 0) xv += pb[i] * (float)NT;
        Xs[i][ml] = xv;
    }
    __syncthreads();
    #pragma unroll
    for (int q = 0; q < 4; ++q) {
        int flat = q * 256 + tid;
        int o = flat >> 4, kl = flat & 15;
        int k = kq * 16 + kl;
        float yr = 0.f, yi = 0.f;
        #pragma unroll 8
        for (int i = 0; i < 64; ++i) {
            float2 xv = *(const float2*)&Xs[i][2 * kl];
            float2 wv = *(const float2*)&fw_l[(((size_t)i * DV + o) * 64 + k) * 2];
            yr = fmaf(xv.x, wv.x, fmaf(xv.y, wv.y, yr));
            yi = fmaf(xv.x, wv.y, fmaf(-xv.y, wv.x, yi));
        }
        int mf = o >> 4, mm = 2 * kl, m1 = mm + 1;
        zfr[((((size_t)b * 4 + kq) * 4 + mf) * 64 + (o & 15) + 16 * (mm >> 3)) * 8 + (mm & 7)] = (_Float16)yr;
        zfr[((((size_t)b * 4 + kq) * 4 + mf) * 64 + (o & 15) + 16 * (m1 >> 3)) * 8 + (m1 & 7)] = (_Float16)(-yi);
    }
}

// ---------------- spectral mix layers 1..3 (frag-ordered partial reduce) ----------------
__launch_bounds__(256)
__global__ void k_spec(const _Float16* __restrict__ xpf, const float* __restrict__ fw_l,
                       _Float16* __restrict__ zfr) {
    __shared__ float Xs[64][32];
    int b = blockIdx.y, kq = blockIdx.x, tid = threadIdx.x;
    float a8[8];
    #pragma unroll
    for (int e = 0; e < 8; ++e) a8[e] = 0.f;
    const half8* src = (const half8*)xpf;
    size_t base8 = ((size_t)b * 4 + kq) * 256 + tid;
    const size_t step8 = (size_t)NB * 4 * 256;
    for (int ks = 0; ks < KSP; ++ks) {
        half8 vv = src[base8 + (size_t)ks * step8];
        #pragma unroll
        for (int e = 0; e < 8; ++e) a8[e] += (float)vv[e];
    }
    int cf = tid >> 6, nf2 = (tid >> 5) & 1, lane0 = (tid & 31) * 2;
    #pragma unroll
    for (int e = 0; e < 8; ++e) {
        int lane = lane0 + (e >> 2), reg = e & 3;
        int g = lane >> 4, r = lane & 15;
        Xs[cf * 16 + g * 4 + reg][nf2 * 16 + r] = a8[e];
    }
    __syncthreads();
    #pragma unroll
    for (int q = 0; q < 4; ++q) {
        int flat = q * 256 + tid;
        int o = flat >> 4, kl = flat & 15;
        int k = kq * 16 + kl;
        float yr = 0.f, yi = 0.f;
        #pragma unroll 8
        for (int i = 0; i < 64; ++i) {
            float2 xv = *(const float2*)&Xs[i][2 * kl];
            float2 wv = *(const float2*)&fw_l[(((size_t)i * DV + o) * 64 + k) * 2];
            yr = fmaf(xv.x, wv.x, fmaf(xv.y, wv.y, yr));
            yi = fmaf(xv.x, wv.y, fmaf(-xv.y, wv.x, yi));
        }
        int mf = o >> 4, mm = 2 * kl, m1 = mm + 1;
        zfr[((((size_t)b * 4 + kq) * 4 + mf) * 64 + (o & 15) + 16 * (mm >> 3)) * 8 + (mm & 7)] = (_Float16)yr;
        zfr[((((size_t)b * 4 + kq) * 4 + mf) * 64 + (o & 15) + 16 * (m1 >> 3)) * 8 + (m1 & 7)] = (_Float16)(-yi);
    }
}

// ---------------- inverse DFT + local + bias (+relu | +q_w reduce), 2 tiles/wave ----------------
// MODE: 0 = FIRST (rank-2 local), 1 = MID, 2 = LAST
// grid (130, NB) for 0/1 (wave owns t in [wid*64, wid*64+64)), (128, NB) for 2.
template <int MODE>
__launch_bounds__(64)
__global__ void k_inv(const _Float16* __restrict__ zfr, const _Float16* __restrict__ tabI,
                      const _Float16* __restrict__ Wl, const float* __restrict__ wb_l,
                      const float* __restrict__ qw, const float* __restrict__ qb,
                      const float* __restrict__ v, const float* __restrict__ grd,
                      const float* __restrict__ A,
                      _Float16* __restrict__ xT, float* __restrict__ out) {
    __shared__ _Float16 xw[2048];        // 4 KiB wave-local transpose tile, reused per sub-tile
    __shared__ float Asm[3][64];         // FIRST
    int b = blockIdx.y;
    int wid = blockIdx.x;
    int lane = threadIdx.x;
    int g = lane >> 4, r = lane & 15;
    int tw0 = wid * 64;
    const half8* zfv = (const half8*)zfr;
    const half8* tIv = (const half8*)tabI;
    const half8* wfv = (const half8*)Wl;

    // ---- hoisted old-x B-frag load, tile 0 (MID/LAST) ----
    half8 xb0[2][2];
    if (MODE != 0) {
        #pragma unroll
        for (int ks = 0; ks < 2; ++ks)
            #pragma unroll
            for (int nf = 0; nf < 2; ++nf)
                xb0[ks][nf] = *(const half8*)&xT[((size_t)b * NPP + tw0 + nf * 16 + r) * 64 + ks * 32 + g * 8];
    }
    if (MODE == 0) {
        Asm[0][lane] = A[lane];
        Asm[1][lane] = A[64 + lane];
        Asm[2][lane] = A[128 + lane];
    }

    f32x4 acc[2][4][2];
    #pragma unroll
    for (int tt = 0; tt < 2; ++tt)
        #pragma unroll
        for (int mf = 0; mf < 4; ++mf)
            #pragma unroll
            for (int nf = 0; nf < 2; ++nf) acc[tt][mf][nf] = (f32x4){0.f, 0.f, 0.f, 0.f};

    // ---- spectral: A=z (shared across both tiles), B=tabI ----
    #pragma unroll
    for (int ks4 = 0; ks4 < 4; ++ks4) {
        half8 az[4], bt0[2], bt1[2];
        #pragma unroll
        for (int mf = 0; mf < 4; ++mf)
            az[mf] = zfv[(((size_t)b * 4 + ks4) * 4 + mf) * 64 + lane];
        #pragma unroll
        for (int nf = 0; nf < 2; ++nf) {
            bt0[nf] = tIv[((size_t)ks4 * TFR + (tw0 >> 4) + nf) * 64 + lane];
            bt1[nf] = tIv[((size_t)ks4 * TFR + (tw0 >> 4) + 2 + nf) * 64 + lane];
        }
        #pragma unroll
        for (int mf = 0; mf < 4; ++mf)
            #pragma unroll
            for (int nf = 0; nf < 2; ++nf) {
                acc[0][mf][nf] = __builtin_amdgcn_mfma_f32_16x16x32_f16(az[mf], bt0[nf], acc[0][mf][nf], 0, 0, 0);
                acc[1][mf][nf] = __builtin_amdgcn_mfma_f32_16x16x32_f16(az[mf], bt1[nf], acc[1][mf][nf], 0, 0, 0);
            }
    }
    // ---- local: (Whi + Wlo) * x  (MID/LAST only), tile-by-tile ----
    half8 xb1[2][2];
    if (MODE != 0) {
        #pragma unroll
        for (int ks = 0; ks < 2; ++ks)
            #pragma unroll
            for (int nf = 0; nf < 2; ++nf)
                xb1[ks][nf] = *(const half8*)&xT[((size_t)b * NPP + tw0 + 32 + nf * 16 + r) * 64 + ks * 32 + g * 8];
        #pragma unroll
        for (int hl = 0; hl < 2; ++hl)
            #pragma unroll
            for (int ks = 0; ks < 2; ++ks) {
                half8 aw[4];
                #pragma unroll
                for (int mf = 0; mf < 4; ++mf)
                    aw[mf] = wfv[((size_t)(hl * 2 + ks) * 4 + mf) * 64 + lane];
                #pragma unroll
                for (int mf = 0; mf < 4; ++mf)
                    #pragma unroll
                    for (int nf = 0; nf < 2; ++nf) {
                        acc[0][mf][nf] = __builtin_amdgcn_mfma_f32_16x16x32_f16(aw[mf], xb0[ks][nf], acc[0][mf][nf], 0, 0, 0);
                        acc[1][mf][nf] = __builtin_amdgcn_mfma_f32_16x16x32_f16(aw[mf], xb1[ks][nf], acc[1][mf][nf], 0, 0, 0);
                    }
            }
    }

    if (MODE != 2) {
        #pragma unroll
        for (int tt = 0; tt < 2; ++tt) {
            int tw = tw0 + tt * 32;
            float vv[2], gg[2];
            if (MODE == 0) {
                #pragma unroll
                for (int nf = 0; nf < 2; ++nf) {
                    int t = tw + nf * 16 + r;
                    bool in = (t < NT);
                    vv[nf] = in ? v[(size_t)b * NT + t] : 0.f;
                    gg[nf] = in ? grd[t] : 0.f;
                }
            }
            // ---- wave-local epilogue: bias(+rank2)+relu -> swizzled LDS -> coalesced store ----
            #pragma unroll
            for (int mf = 0; mf < 4; ++mf)
                #pragma unroll
                for (int nf = 0; nf < 2; ++nf) {
                    int tl = nf * 16 + r;
                    half4 h4;
                    #pragma unroll
                    for (int reg = 0; reg < 4; ++reg) {
                        int o = mf * 16 + g * 4 + reg;
                        float val = acc[tt][mf][nf][reg] + wb_l[o];
                        if (MODE == 0)
                            val += fmaf(Asm[0][o], vv[nf], fmaf(Asm[1][o], gg[nf], Asm[2][o]));
                        h4[reg] = (_Float16)fmaxf(val, 0.f);
                    }
                    int idx = tl * 64 + ((mf * 16 + g * 4) ^ ((tl & 7) << 3));
                    *(half4*)&xw[idx] = h4;
                }
            #pragma unroll
            for (int it = 0; it < 4; ++it) {
                int t = it * 8 + (lane >> 3);
                int cg = lane & 7;
                half8 vv8 = *(const half8*)&xw[t * 64 + ((cg * 8) ^ ((t & 7) << 3))];
                *(half8*)&xT[((size_t)b * NPP + tw + t) * 64 + cg * 8] = vv8;
            }
        }
    } else {
        float qbv = qb[0];
        #pragma unroll
        for (int tt = 0; tt < 2; ++tt) {
            int tw = tw0 + tt * 32;
            float p0 = 0.f, p1 = 0.f;
            #pragma unroll
            for (int mf = 0; mf < 4; ++mf)
                #pragma unroll
                for (int reg = 0; reg < 4; ++reg) {
                    int o = mf * 16 + g * 4 + reg;
                    float qq = qw[o], bias = wb_l[o];
                    p0 = fmaf(acc[tt][mf][0][reg] + bias, qq, p0);
                    p1 = fmaf(acc[tt][mf][1][reg] + bias, qq, p1);
                }
            p0 += __shfl_xor(p0, 16); p0 += __shfl_xor(p0, 32);
            p1 += __shfl_xor(p1, 16); p1 += __shfl_xor(p1, 32);
            if (g == 0) out[(size_t)b * NT + tw + r]      = p0 + qbv;
            if (g == 1) out[(size_t)b * NT + tw + 16 + r] = p1 + qbv;
        }
    }
}

extern "C" void kernel_launch(void* const* d_in, const int* in_sizes, int n_in,
                              void* d_out, int out_size, void* d_ws, size_t ws_size,
                              hipStream_t stream) {
    const float* v   = (const float*)d_in[0];
    const float* grd = (const float*)d_in[1];
    const float* pw  = (const float*)d_in[2];
    const float* pb  = (const float*)d_in[3];
    const float* fw  = (const float*)d_in[4];
    const float* ww  = (const float*)d_in[5];
    const float* wb  = (const float*)d_in[6];
    const float* qw  = (const float*)d_in[7];
    const float* qb  = (const float*)d_in[8];
    float* out = (float*)d_out;

    char* wsb = (char*)d_ws;
    _Float16* xT    = (_Float16*)(wsb + B_XT);
    _Float16* tabFb = (_Float16*)(wsb + B_TABF);
    _Float16* tabIb = (_Float16*)(wsb + B_TABI);
    _Float16* Wfrag = (_Float16*)(wsb + B_WFR);
    _Float16* zfrag = (_Float16*)(wsb + B_ZFR);
    _Float16* xpf   = (_Float16*)(wsb + B_XPF);
    _Float16* Vpart = (_Float16*)(wsb + B_VP);
    float*    G     = (float*)(wsb + B_G);
    float*    A     = (float*)(wsb + B_A);

    k_prep_all<<<713, 256, 0, stream>>>(ww, pw, pb, grd, tabFb, tabIb, Wfrag, A, G);
    k_fdft_v<<<KSP, 256, 0, stream>>>(v, tabFb, Vpart);

    for (int l = 0; l < NL; ++l) {
        if (l == 0) {
            k_spec0<<<dim3(4, NB), 256, 0, stream>>>(Vpart, G, pw, pb, fw, zfrag);
        } else {
            k_fdft<<<dim3(KSP, NB), 256, 0, stream>>>(xT, tabFb, xpf);
            k_spec<<<dim3(4, NB), 256, 0, stream>>>(xpf, fw + (size_t)l * DV * DV * 64 * 2, zfrag);
        }
        const _Float16* wf_l = Wfrag + (size_t)l * 8192;   // 2*2*4*64*8 per layer
        const float* wb_l = wb + (size_t)l * DV;
        if (l == 0)
            k_inv<0><<<dim3(130, NB), 64, 0, stream>>>(
                zfrag, tabIb, wf_l, wb_l, qw, qb, v, grd, A, xT, out);
        else if (l < NL - 1)
            k_inv<1><<<dim3(130, NB), 64, 0, stream>>>(
                zfrag, tabIb, wf_l, wb_l, qw, qb, v, grd, A, xT, out);
        else
            k_inv<2><<<dim3(128, NB), 64, 0, stream>>>(
                zfrag, tabIb, wf_l, wb_l, qw, qb, v, grd, A, xT, out);
    }
}